// Round 1
// baseline (508.913 us; speedup 1.0000x reference)
//
#include <hip/hip_runtime.h>

// MultiHeadQKVAttention: B=4, N=M=2048, DK=DV=DKP=DVP=1024, H=16, dh=dv=64.
// Pipeline: cvt(f32->bf16) -> 3x proj GEMM (bf16 MFMA) -> V transpose ->
// flash attention -> output GEMM (f32 out).

#define DI __device__ __forceinline__

typedef float f32x4 __attribute__((ext_vector_type(4)));
typedef __bf16 bf16x8 __attribute__((ext_vector_type(8)));
typedef unsigned short ushort8v __attribute__((ext_vector_type(8)));

typedef const __attribute__((address_space(1))) void gvoid_t;
typedef __attribute__((address_space(3))) void lvoid_t;

DI unsigned short f2b(float f) { return __builtin_bit_cast(unsigned short, (__bf16)f); }

DI void gload16(const void* g, void* l) {
  __builtin_amdgcn_global_load_lds((gvoid_t*)g, (lvoid_t*)l, 16, 0, 0);
}

// ---------------- f32 -> bf16 convert (vectorized) ----------------
__global__ __launch_bounds__(256) void cvt_kernel(const float* __restrict__ in,
                                                  unsigned short* __restrict__ out, int n4) {
  int i = blockIdx.x * 256 + threadIdx.x;
  if (i < n4) {
    float4 v = ((const float4*)in)[i];
    ushort4 o;
    o.x = f2b(v.x); o.y = f2b(v.y); o.z = f2b(v.z); o.w = f2b(v.w);
    ((ushort4*)out)[i] = o;
  }
}

// ---------------- weight transpose+convert: W[K][N] f32 -> Wt[N][K] bf16 ----------------
__global__ __launch_bounds__(256) void wtrans_kernel(const float* __restrict__ in,
                                                     unsigned short* __restrict__ out) {
  __shared__ float t[32][33];
  const int n0 = blockIdx.x * 32, k0 = blockIdx.y * 32;
  const int tx = threadIdx.x, ty = threadIdx.y;
#pragma unroll
  for (int i = 0; i < 4; ++i)
    t[ty + i * 8][tx] = in[(size_t)(k0 + ty + i * 8) * 1024 + n0 + tx];
  __syncthreads();
#pragma unroll
  for (int i = 0; i < 4; ++i)
    out[(size_t)(n0 + ty + i * 8) * 1024 + k0 + tx] = f2b(t[tx][ty + i * 8]);
}

// ---------------- V transpose per head: vb[B][M][H*64] -> vT[B][H][64][M] ----------------
__global__ __launch_bounds__(256) void vtrans_kernel(const unsigned short* __restrict__ vb,
                                                     unsigned short* __restrict__ vTg) {
  __shared__ unsigned short t[64][66];  // 66: odd-dword row stride -> ~2-way on col reads
  const int m0 = blockIdx.x * 64;
  const int h = blockIdx.y, b = blockIdx.z;
  const int tid = (int)threadIdx.x;
#pragma unroll
  for (int i = 0; i < 2; ++i) {
    int idx = i * 256 + tid;       // 0..511
    int row = idx >> 3;            // m offset 0..63
    int d0 = (idx & 7) * 8;
    ushort8v v = *(const ushort8v*)(vb + ((size_t)(b * 2048 + m0 + row) * 16 + h) * 64 + d0);
#pragma unroll
    for (int j = 0; j < 8; ++j) t[row][d0 + j] = v[j];
  }
  __syncthreads();
#pragma unroll
  for (int i = 0; i < 2; ++i) {
    int idx = i * 256 + tid;
    int d = idx >> 3;
    int mo = (idx & 7) * 8;
    ushort8v o;
#pragma unroll
    for (int j = 0; j < 8; ++j) o[j] = t[mo + j][d];
    *(ushort8v*)(vTg + (((size_t)(b * 16 + h) * 64 + d) * 2048 + m0 + mo)) = o;
  }
}

// ---------------- GEMM: C[.][Ng] = A[.][Kg](bf16) @ Bt[Ng][Kg]^T(bf16) + bias ----------------
// 128x128 tile, BK=64, 4 waves (2x2), 16x16x32 bf16 MFMA.
// LDS tiles are [row][64] bf16 (128B rows); XOR swizzle byte^=((row&7)<<4),
// applied as inverse-swizzled global source (linear global_load_lds dest) + swizzled reads.
template <typename CT>
__global__ __launch_bounds__(256, 2) void gemm_bt_kernel(const unsigned short* __restrict__ A,
                                                         const unsigned short* __restrict__ Bt,
                                                         const float* __restrict__ bias,
                                                         CT* __restrict__ C, int Ng, int Kg) {
  __shared__ unsigned short ldsA[128 * 64];
  __shared__ unsigned short ldsB[128 * 64];

  const int nbx = Ng >> 7;
  const int nwg = gridDim.x;
  const int cpx = nwg >> 3;  // grid divisible by 8
  const int wg0 = (int)blockIdx.x;
  const int wg = (wg0 & 7) * cpx + (wg0 >> 3);  // XCD-aware bijective swizzle
  const int by = wg / nbx, bx = wg % nbx;

  const int tid = (int)threadIdx.x;
  const int w = tid >> 6, lane = tid & 63;
  const int lq = lane >> 4, lr = lane & 15;
  const int wr = w >> 1, wc = w & 1;

  const size_t rowA = (size_t)by * 128;
  const int colB = bx * 128;

  f32x4 acc[4][4];
#pragma unroll
  for (int m = 0; m < 4; ++m)
#pragma unroll
    for (int n = 0; n < 4; ++n) acc[m][n] = f32x4{0.f, 0.f, 0.f, 0.f};

  for (int k0 = 0; k0 < Kg; k0 += 64) {
#pragma unroll
    for (int i = 0; i < 4; ++i) {
      const int c = w * 4 + i;                 // 16 chunks of 1KB
      const int off = c * 1024 + lane * 16;    // linear LDS byte pos this lane fills
      const int row = off >> 7;
      const int kbs = (off & 127) ^ ((row & 7) << 4);  // inverse-swizzled source col
      gload16(A + ((rowA + row) * (size_t)Kg + k0 + (kbs >> 1)), &ldsA[c * 512]);
      gload16(Bt + ((size_t)(colB + row) * Kg + k0 + (kbs >> 1)), &ldsB[c * 512]);
    }
    __syncthreads();
#pragma unroll
    for (int kk = 0; kk < 2; ++kk) {
      const int kbyte = kk * 64 + lq * 16;
      bf16x8 af[4], bfv[4];
#pragma unroll
      for (int m = 0; m < 4; ++m) {
        const int row = wr * 64 + m * 16 + lr;
        af[m] = *(const bf16x8*)((const char*)ldsA + row * 128 + (kbyte ^ ((row & 7) << 4)));
      }
#pragma unroll
      for (int n = 0; n < 4; ++n) {
        const int row = wc * 64 + n * 16 + lr;
        bfv[n] = *(const bf16x8*)((const char*)ldsB + row * 128 + (kbyte ^ ((row & 7) << 4)));
      }
#pragma unroll
      for (int m = 0; m < 4; ++m)
#pragma unroll
        for (int n = 0; n < 4; ++n)
          acc[m][n] = __builtin_amdgcn_mfma_f32_16x16x32_bf16(af[m], bfv[n], acc[m][n], 0, 0, 0);
    }
    __syncthreads();
  }

#pragma unroll
  for (int n = 0; n < 4; ++n) {
    const int col = colB + wc * 64 + n * 16 + lr;
    const float bvl = bias[col];
#pragma unroll
    for (int m = 0; m < 4; ++m) {
      const size_t r0 = rowA + wr * 64 + m * 16 + lq * 4;
#pragma unroll
      for (int r = 0; r < 4; ++r) {
        const float v = acc[m][n][r] + bvl;
        if constexpr (sizeof(CT) == 2)
          C[(r0 + r) * Ng + col] = f2b(v);
        else
          C[(r0 + r) * Ng + col] = v;
      }
    }
  }
}

// ---------------- Flash attention ----------------
// Block = 4 waves, 64 q-rows (16/wave), KVBLK=64, dh=dv=64.
// Q: bf16 [B][N][H*64]; K: bf16 [B][M][H*64]; Vt: bf16 [B][H][64][M]; O: bf16 [B][N][H*64].
__global__ __launch_bounds__(256, 3) void attn_kernel(const unsigned short* __restrict__ Q,
                                                      const unsigned short* __restrict__ K,
                                                      const unsigned short* __restrict__ Vt,
                                                      const float* __restrict__ presence,
                                                      unsigned short* __restrict__ O) {
  __shared__ unsigned short kT[64 * 64];    // [key][d], swizzled
  __shared__ unsigned short vT[64 * 64];    // [d][key], swizzled
  __shared__ unsigned short pL[4][16 * 64]; // per-wave P tile [row][key], swizzled

  const int q0 = blockIdx.x * 64;
  const int h = blockIdx.y, b = blockIdx.z;
  const int tid = (int)threadIdx.x;
  const int w = tid >> 6, lane = tid & 63;
  const int lq = lane >> 4, lr = lane & 15;

  // Q fragments (A-operand): row = lr, k = kk*32 + lq*8 .. +8
  const unsigned short* qp = Q + ((size_t)(b * 2048 + q0 + w * 16 + lr) * 1024 + h * 64);
  const bf16x8 qf0 = *(const bf16x8*)(qp + lq * 8);
  const bf16x8 qf1 = *(const bf16x8*)(qp + 32 + lq * 8);

  f32x4 accO[4];
  float mrun[4], lrun[4];
#pragma unroll
  for (int r = 0; r < 4; ++r) {
    accO[r] = f32x4{0.f, 0.f, 0.f, 0.f};
    mrun[r] = -3.0e38f;
    lrun[r] = 0.f;
  }

  const float* pres = presence + b * 2048;
  const float LOG2E = 1.4426950408889634f;

  for (int m0 = 0; m0 < 2048; m0 += 64) {
    // stage K[key][d] and Vt[d][key] tiles (8KB each, swizzled source)
#pragma unroll
    for (int i = 0; i < 2; ++i) {
      const int c = w * 2 + i;
      const int off = c * 1024 + lane * 16;
      const int row = off >> 7;
      const int kbs = (off & 127) ^ ((row & 7) << 4);
      gload16(K + ((size_t)(b * 2048 + m0 + row) * 1024 + h * 64 + (kbs >> 1)), &kT[c * 512]);
      gload16(Vt + (((size_t)(b * 16 + h) * 64 + row) * 2048 + m0 + (kbs >> 1)), &vT[c * 512]);
    }
    __syncthreads();

    // S = Q K^T  (S[q][key], 4 col-fragments of 16 keys)
    f32x4 s[4];
#pragma unroll
    for (int cf = 0; cf < 4; ++cf) s[cf] = f32x4{0.f, 0.f, 0.f, 0.f};
#pragma unroll
    for (int kk = 0; kk < 2; ++kk) {
      const int kbyte = kk * 64 + lq * 16;
      const bf16x8 qf = kk ? qf1 : qf0;
#pragma unroll
      for (int cf = 0; cf < 4; ++cf) {
        const int key = cf * 16 + lr;
        const bf16x8 kf =
            *(const bf16x8*)((const char*)kT + key * 128 + (kbyte ^ ((key & 7) << 4)));
        s[cf] = __builtin_amdgcn_mfma_f32_16x16x32_bf16(qf, kf, s[cf], 0, 0, 0);
      }
    }

    // scaled + masked logits
    float x[4][4];
#pragma unroll
    for (int cf = 0; cf < 4; ++cf) {
      const float msk = (pres[m0 + cf * 16 + lr] - 1.0f) * 1.0e31f;
#pragma unroll
      for (int r = 0; r < 4; ++r) x[cf][r] = s[cf][r] * 0.125f + msk;
    }
    // wave-parallel row max (rows live as reg r across 16-lane groups)
    float rm[4];
#pragma unroll
    for (int r = 0; r < 4; ++r)
      rm[r] = fmaxf(fmaxf(x[0][r], x[1][r]), fmaxf(x[2][r], x[3][r]));
#pragma unroll
    for (int st = 0; st < 4; ++st) {
      const int d = 1 << st;
#pragma unroll
      for (int r = 0; r < 4; ++r) rm[r] = fmaxf(rm[r], __shfl_xor(rm[r], d, 64));
    }

    float al[4], rs[4];
#pragma unroll
    for (int r = 0; r < 4; ++r) {
      const float mn = fmaxf(mrun[r], rm[r]);
      al[r] = exp2f((mrun[r] - mn) * LOG2E);
      mrun[r] = mn;
      rs[r] = 0.f;
    }
    // P = exp(x - m), write bf16 to per-wave LDS (swizzled) for A-fragment relayout
#pragma unroll
    for (int cf = 0; cf < 4; ++cf)
#pragma unroll
      for (int r = 0; r < 4; ++r) {
        const float p = exp2f((x[cf][r] - mrun[r]) * LOG2E);
        rs[r] += p;
        const int row = lq * 4 + r, key = cf * 16 + lr;
        *(unsigned short*)((char*)pL[w] + row * 128 + ((key * 2) ^ ((row & 7) << 4))) = f2b(p);
      }
#pragma unroll
    for (int st = 0; st < 4; ++st) {
      const int d = 1 << st;
#pragma unroll
      for (int r = 0; r < 4; ++r) rs[r] += __shfl_xor(rs[r], d, 64);
    }
#pragma unroll
    for (int r = 0; r < 4; ++r) lrun[r] = lrun[r] * al[r] + rs[r];
#pragma unroll
    for (int df = 0; df < 4; ++df)
#pragma unroll
      for (int r = 0; r < 4; ++r) accO[df][r] *= al[r];

    // O += P V
#pragma unroll
    for (int kc = 0; kc < 2; ++kc) {
      const int kbyte = kc * 64 + lq * 16;
      const bf16x8 pa =
          *(const bf16x8*)((const char*)pL[w] + lr * 128 + (kbyte ^ ((lr & 7) << 4)));
#pragma unroll
      for (int df = 0; df < 4; ++df) {
        const int d = df * 16 + lr;
        const bf16x8 vf =
            *(const bf16x8*)((const char*)vT + d * 128 + (kbyte ^ ((d & 7) << 4)));
        accO[df] = __builtin_amdgcn_mfma_f32_16x16x32_bf16(pa, vf, accO[df], 0, 0, 0);
      }
    }
    __syncthreads();
  }

#pragma unroll
  for (int df = 0; df < 4; ++df)
#pragma unroll
    for (int r = 0; r < 4; ++r) {
      const float v = accO[df][r] / lrun[r];
      const size_t g = (size_t)(b * 2048 + q0 + w * 16 + lq * 4 + r);
      O[g * 1024 + h * 64 + df * 16 + lr] = f2b(v);
    }
}

// ---------------- launch ----------------
extern "C" void kernel_launch(void* const* d_in, const int* in_sizes, int n_in,
                              void* d_out, int out_size, void* d_ws, size_t ws_size,
                              hipStream_t stream) {
  const float* queries = (const float*)d_in[0];
  const float* keys = (const float*)d_in[1];
  const float* values = (const float*)d_in[2];
  const float* presence = (const float*)d_in[3];
  // d_in[4] = n_heads (16, hardcoded)
  const float* wq = (const float*)d_in[5];
  const float* bq = (const float*)d_in[6];
  const float* wk = (const float*)d_in[7];
  const float* bk = (const float*)d_in[8];
  const float* wv = (const float*)d_in[9];
  const float* bv = (const float*)d_in[10];
  const float* wo = (const float*)d_in[11];
  const float* bo = (const float*)d_in[12];
  float* out = (float*)d_out;

  char* ws = (char*)d_ws;
  // buffers (bf16): inb reused as attention output
  unsigned short* inb = (unsigned short*)(ws + (size_t)0);          // 16 MiB [8192][1024]
  unsigned short* qb  = (unsigned short*)(ws + (size_t)16777216);   // 16 MiB
  unsigned short* kb  = (unsigned short*)(ws + (size_t)33554432);   // 16 MiB
  unsigned short* vb  = (unsigned short*)(ws + (size_t)50331648);   // 16 MiB
  unsigned short* vTg = (unsigned short*)(ws + (size_t)67108864);   // 16 MiB [B][H][64][M]
  unsigned short* wqT = (unsigned short*)(ws + (size_t)83886080);   // 2 MiB each
  unsigned short* wkT = wqT + 1048576;
  unsigned short* wvT = wkT + 1048576;
  unsigned short* woT = wvT + 1048576;

  const dim3 wtg(32, 32), wtb(32, 8);
  const dim3 vtg(32, 16, 4);
  const dim3 atg(32, 16, 4);
  const int cvtBlocks = 8192;  // 2097152 float4s / 256

  cvt_kernel<<<cvtBlocks, 256, 0, stream>>>(queries, inb, 2097152);
  wtrans_kernel<<<wtg, wtb, 0, stream>>>(wq, wqT);
  gemm_bt_kernel<unsigned short><<<512, 256, 0, stream>>>(inb, wqT, bq, qb, 1024, 1024);

  cvt_kernel<<<cvtBlocks, 256, 0, stream>>>(keys, inb, 2097152);
  wtrans_kernel<<<wtg, wtb, 0, stream>>>(wk, wkT);
  gemm_bt_kernel<unsigned short><<<512, 256, 0, stream>>>(inb, wkT, bk, kb, 1024, 1024);

  cvt_kernel<<<cvtBlocks, 256, 0, stream>>>(values, inb, 2097152);
  wtrans_kernel<<<wtg, wtb, 0, stream>>>(wv, wvT);
  gemm_bt_kernel<unsigned short><<<512, 256, 0, stream>>>(inb, wvT, bv, vb, 1024, 1024);

  vtrans_kernel<<<vtg, 256, 0, stream>>>(vb, vTg);

  attn_kernel<<<atg, 256, 0, stream>>>(qb, kb, vTg, presence, inb);

  wtrans_kernel<<<wtg, wtb, 0, stream>>>(wo, woT);
  gemm_bt_kernel<float><<<512, 256, 0, stream>>>(inb, woT, bo, out, 1024, 1024);
}

// Round 3
// 419.347 us; speedup vs baseline: 1.2136x; 1.2136x over previous
//
#include <hip/hip_runtime.h>

// MultiHeadQKVAttention: B=4, N=M=2048, DK=DV=DKP=DVP=1024, H=16, dh=dv=64.
// Pipeline: cvt(f32->bf16) -> 3x proj GEMM (bf16 MFMA) -> V transpose ->
// flash attention (swapped-operand, in-register softmax) -> output GEMM.

#define DI __device__ __forceinline__

typedef float f32x4 __attribute__((ext_vector_type(4)));
typedef __bf16 bf16x8 __attribute__((ext_vector_type(8)));
typedef unsigned short ushort8v __attribute__((ext_vector_type(8)));

typedef const __attribute__((address_space(1))) void gvoid_t;
typedef __attribute__((address_space(3))) void lvoid_t;

DI unsigned short f2b(float f) { return __builtin_bit_cast(unsigned short, (__bf16)f); }

DI void gload16(const void* g, void* l) {
  __builtin_amdgcn_global_load_lds((gvoid_t*)g, (lvoid_t*)l, 16, 0, 0);
}

// ---------------- f32 -> bf16 convert (vectorized) ----------------
__global__ __launch_bounds__(256) void cvt_kernel(const float* __restrict__ in,
                                                  unsigned short* __restrict__ out, int n4) {
  int i = blockIdx.x * 256 + threadIdx.x;
  if (i < n4) {
    float4 v = ((const float4*)in)[i];
    ushort4 o;
    o.x = f2b(v.x); o.y = f2b(v.y); o.z = f2b(v.z); o.w = f2b(v.w);
    ((ushort4*)out)[i] = o;
  }
}

// ---------------- mask precompute: pm[b][m] = (pres-1)*1e32*0.125*log2e ----------------
__global__ __launch_bounds__(256) void mask_kernel(const float* __restrict__ pres,
                                                   float* __restrict__ pm, int n) {
  int i = blockIdx.x * 256 + threadIdx.x;
  if (i < n) pm[i] = (pres[i] - 1.0f) * 1.8033688011112042e31f;
}

// ---------------- weight transpose+convert: W[K][N] f32 -> Wt[N][K] bf16 ----------------
__global__ __launch_bounds__(256) void wtrans_kernel(const float* __restrict__ in,
                                                     unsigned short* __restrict__ out) {
  __shared__ float t[32][33];
  const int n0 = blockIdx.x * 32, k0 = blockIdx.y * 32;
  const int tx = threadIdx.x, ty = threadIdx.y;
#pragma unroll
  for (int i = 0; i < 4; ++i)
    t[ty + i * 8][tx] = in[(size_t)(k0 + ty + i * 8) * 1024 + n0 + tx];
  __syncthreads();
#pragma unroll
  for (int i = 0; i < 4; ++i)
    out[(size_t)(n0 + ty + i * 8) * 1024 + k0 + tx] = f2b(t[tx][ty + i * 8]);
}

// ---------------- V transpose per head: vb[B][M][H*64] -> vT[B][H][64][M] ----------------
__global__ __launch_bounds__(256) void vtrans_kernel(const unsigned short* __restrict__ vb,
                                                     unsigned short* __restrict__ vTg) {
  __shared__ unsigned short t[64][66];
  const int m0 = blockIdx.x * 64;
  const int h = blockIdx.y, b = blockIdx.z;
  const int tid = (int)threadIdx.x;
#pragma unroll
  for (int i = 0; i < 2; ++i) {
    int idx = i * 256 + tid;
    int row = idx >> 3;
    int d0 = (idx & 7) * 8;
    ushort8v v = *(const ushort8v*)(vb + ((size_t)(b * 2048 + m0 + row) * 16 + h) * 64 + d0);
#pragma unroll
    for (int j = 0; j < 8; ++j) t[row][d0 + j] = v[j];
  }
  __syncthreads();
#pragma unroll
  for (int i = 0; i < 2; ++i) {
    int idx = i * 256 + tid;
    int d = idx >> 3;
    int mo = (idx & 7) * 8;
    ushort8v o;
#pragma unroll
    for (int j = 0; j < 8; ++j) o[j] = t[mo + j][d];
    *(ushort8v*)(vTg + (((size_t)(b * 16 + h) * 64 + d) * 2048 + m0 + mo)) = o;
  }
}

// ---------------- GEMM: C[.][Ng] = A[.][Kg](bf16) @ Bt[Ng][Kg]^T(bf16) + bias ----------------
template <typename CT>
__global__ __launch_bounds__(256, 2) void gemm_bt_kernel(const unsigned short* __restrict__ A,
                                                         const unsigned short* __restrict__ Bt,
                                                         const float* __restrict__ bias,
                                                         CT* __restrict__ C, int Ng, int Kg) {
  __shared__ unsigned short ldsA[128 * 64];
  __shared__ unsigned short ldsB[128 * 64];

  const int nbx = Ng >> 7;
  const int nwg = gridDim.x;
  const int cpx = nwg >> 3;
  const int wg0 = (int)blockIdx.x;
  const int wg = (wg0 & 7) * cpx + (wg0 >> 3);
  const int by = wg / nbx, bx = wg % nbx;

  const int tid = (int)threadIdx.x;
  const int w = tid >> 6, lane = tid & 63;
  const int lq = lane >> 4, lr = lane & 15;
  const int wr = w >> 1, wc = w & 1;

  const size_t rowA = (size_t)by * 128;
  const int colB = bx * 128;

  f32x4 acc[4][4];
#pragma unroll
  for (int m = 0; m < 4; ++m)
#pragma unroll
    for (int n = 0; n < 4; ++n) acc[m][n] = f32x4{0.f, 0.f, 0.f, 0.f};

  for (int k0 = 0; k0 < Kg; k0 += 64) {
#pragma unroll
    for (int i = 0; i < 4; ++i) {
      const int c = w * 4 + i;
      const int off = c * 1024 + lane * 16;
      const int row = off >> 7;
      const int kbs = (off & 127) ^ ((row & 7) << 4);
      gload16(A + ((rowA + row) * (size_t)Kg + k0 + (kbs >> 1)), &ldsA[c * 512]);
      gload16(Bt + ((size_t)(colB + row) * Kg + k0 + (kbs >> 1)), &ldsB[c * 512]);
    }
    __syncthreads();
#pragma unroll
    for (int kk = 0; kk < 2; ++kk) {
      const int kbyte = kk * 64 + lq * 16;
      bf16x8 af[4], bfv[4];
#pragma unroll
      for (int m = 0; m < 4; ++m) {
        const int row = wr * 64 + m * 16 + lr;
        af[m] = *(const bf16x8*)((const char*)ldsA + row * 128 + (kbyte ^ ((row & 7) << 4)));
      }
#pragma unroll
      for (int n = 0; n < 4; ++n) {
        const int row = wc * 64 + n * 16 + lr;
        bfv[n] = *(const bf16x8*)((const char*)ldsB + row * 128 + (kbyte ^ ((row & 7) << 4)));
      }
#pragma unroll
      for (int m = 0; m < 4; ++m)
#pragma unroll
        for (int n = 0; n < 4; ++n)
          acc[m][n] = __builtin_amdgcn_mfma_f32_16x16x32_bf16(af[m], bfv[n], acc[m][n], 0, 0, 0);
    }
    __syncthreads();
  }

#pragma unroll
  for (int n = 0; n < 4; ++n) {
    const int col = colB + wc * 64 + n * 16 + lr;
    const float bvl = bias[col];
#pragma unroll
    for (int m = 0; m < 4; ++m) {
      const size_t r0 = rowA + wr * 64 + m * 16 + lq * 4;
#pragma unroll
      for (int r = 0; r < 4; ++r) {
        const float v = acc[m][n][r] + bvl;
        if constexpr (sizeof(CT) == 2)
          C[(r0 + r) * Ng + col] = f2b(v);
        else
          C[(r0 + r) * Ng + col] = v;
      }
    }
  }
}

// ---------------- Flash attention (swapped operands, in-register softmax) ----------------
// Block = 4 waves, 128 q-rows (2 subtiles of 16 per wave), KVBLK=64, dh=dv=64.
// QK^T swapped: S^T[key][q] = mfma(A=Kfrag, B=Qfrag) -> lane owns q=lr, keys 16kf+lq*4+r.
// PV swapped:   O^T[d][q]   = mfma(A=Vtfrag, B=P^Tfrag) -> lane owns q=lr, d=16df+lq*4+r.
DI void softmax_sub(f32x4 s[4], float& mrun, float& lrun, f32x4 acc[4],
                    char* pbase, const int* pW) {
  float rm = fmaxf(fmaxf(s[0][0], s[0][1]), fmaxf(s[0][2], s[0][3]));
#pragma unroll
  for (int kf = 1; kf < 4; ++kf)
    rm = fmaxf(rm, fmaxf(fmaxf(s[kf][0], s[kf][1]), fmaxf(s[kf][2], s[kf][3])));
  rm = fmaxf(rm, __shfl_xor(rm, 16, 64));
  rm = fmaxf(rm, __shfl_xor(rm, 32, 64));
  if (__any(rm > mrun + 8.0f)) {  // defer-max (T13): only rescale on real growth
    const float mn = fmaxf(mrun, rm);
    const float al = exp2f(mrun - mn);
    lrun *= al;
#pragma unroll
    for (int df = 0; df < 4; ++df) acc[df] *= al;
    mrun = mn;
  }
  float rs = 0.f;
#pragma unroll
  for (int kf = 0; kf < 4; ++kf)
#pragma unroll
    for (int r = 0; r < 4; ++r) {
      const float p = exp2f(s[kf][r] - mrun);
      s[kf][r] = p;
      rs += p;
    }
  rs += __shfl_xor(rs, 16, 64);
  rs += __shfl_xor(rs, 32, 64);
  lrun += rs;
#pragma unroll
  for (int kf = 0; kf < 4; ++kf) {
    ushort4 pk;
    pk.x = f2b(s[kf][0]); pk.y = f2b(s[kf][1]);
    pk.z = f2b(s[kf][2]); pk.w = f2b(s[kf][3]);
    *(ushort4*)(pbase + pW[kf]) = pk;  // 4 consecutive keys, ds_write_b64
  }
}

__global__ __launch_bounds__(256, 4) void attn_kernel(const unsigned short* __restrict__ Q,
                                                      const unsigned short* __restrict__ K,
                                                      const unsigned short* __restrict__ Vt,
                                                      const float* __restrict__ pm,
                                                      unsigned short* __restrict__ O) {
  __shared__ unsigned short kT[64 * 64];       // [key][d] swizzled (8KB)
  __shared__ unsigned short vT[64 * 64];       // [d][key] swizzled (8KB)
  __shared__ unsigned short pL[4][2][16 * 64]; // per-wave/subtile P^T [q][key] swizzled (16KB)

  const int q0 = blockIdx.x * 128;
  const int h = blockIdx.y, b = blockIdx.z;
  const int tid = (int)threadIdx.x;
  const int w = tid >> 6, lane = tid & 63;
  const int lq = lane >> 4, lr = lane & 15;

  // Q fragments (B-operand): col=q=lr, k = kk*32 + lq*8 .. +7
  const unsigned short* qp = Q + ((size_t)(b * 2048 + q0 + w * 32 + lr) * 1024 + h * 64);
  const bf16x8 qfA0 = *(const bf16x8*)(qp + lq * 8);
  const bf16x8 qfA1 = *(const bf16x8*)(qp + 32 + lq * 8);
  const bf16x8 qfB0 = *(const bf16x8*)(qp + 16384 + lq * 8);
  const bf16x8 qfB1 = *(const bf16x8*)(qp + 16384 + 32 + lq * 8);

  // per-lane LDS byte offsets (loop-invariant)
  const int s7 = (lr & 7) << 4;
  const int rd0 = lr * 128 + ((lq * 16) ^ s7);         // kk=0 frag read (K/V/P)
  const int rd1 = lr * 128 + ((64 + lq * 16) ^ s7);    // kk=1
  int pW[4];
#pragma unroll
  for (int kf = 0; kf < 4; ++kf) pW[kf] = lr * 128 + (((kf * 32) + lq * 8) ^ s7);

  // staging: chunks c = w*2 + {0,1}; row = c*8 + lane/8, col = (lane&7)*16 inv-swizzled
  const int rowS0 = w * 16 + (lane >> 3), rowS1 = rowS0 + 8;
  const int colS0 = ((lane & 7) * 16) ^ ((rowS0 & 7) << 4);
  const int colS1 = ((lane & 7) * 16) ^ ((rowS1 & 7) << 4);
  const unsigned short* Kb = K + (size_t)(b * 2048) * 1024 + h * 64;
  const unsigned short* Vb = Vt + (size_t)((b * 16 + h) * 64) * 2048;
  const float* pmB = pm + b * 2048;

  f32x4 accA[4], accB[4];
#pragma unroll
  for (int df = 0; df < 4; ++df) {
    accA[df] = f32x4{0.f, 0.f, 0.f, 0.f};
    accB[df] = f32x4{0.f, 0.f, 0.f, 0.f};
  }
  float mA = -3.0e38f, lA = 0.f, mB = -3.0e38f, lB = 0.f;

  for (int m0 = 0; m0 < 2048; m0 += 64) {
    gload16(Kb + (size_t)(m0 + rowS0) * 1024 + (colS0 >> 1), &kT[(w * 2) * 512]);
    gload16(Vb + (size_t)rowS0 * 2048 + m0 + (colS0 >> 1), &vT[(w * 2) * 512]);
    gload16(Kb + (size_t)(m0 + rowS1) * 1024 + (colS1 >> 1), &kT[(w * 2 + 1) * 512]);
    gload16(Vb + (size_t)rowS1 * 2048 + m0 + (colS1 >> 1), &vT[(w * 2 + 1) * 512]);
    __syncthreads();

    // S^T = K Q^T : s[kf] holds keys 16kf+lq*4+r for q=lr
    f32x4 sA[4], sB[4];
#pragma unroll
    for (int kf = 0; kf < 4; ++kf) {
      sA[kf] = f32x4{0.f, 0.f, 0.f, 0.f};
      sB[kf] = f32x4{0.f, 0.f, 0.f, 0.f};
    }
#pragma unroll
    for (int kk = 0; kk < 2; ++kk) {
      const int rdk = kk ? rd1 : rd0;
      const bf16x8 qa = kk ? qfA1 : qfA0;
      const bf16x8 qb = kk ? qfB1 : qfB0;
#pragma unroll
      for (int kf = 0; kf < 4; ++kf) {
        const bf16x8 kfr = *(const bf16x8*)((const char*)kT + rdk + kf * 2048);
        sA[kf] = __builtin_amdgcn_mfma_f32_16x16x32_bf16(kfr, qa, sA[kf], 0, 0, 0);
        sB[kf] = __builtin_amdgcn_mfma_f32_16x16x32_bf16(kfr, qb, sB[kf], 0, 0, 0);
      }
    }

    // scale to log2 domain + additive mask (pre-scaled): one fma per element
    const float SC = 0.18033688011112042f;  // 0.125 * log2(e)
#pragma unroll
    for (int kf = 0; kf < 4; ++kf) {
      const f32x4 pv = *(const f32x4*)(pmB + m0 + kf * 16 + lq * 4);
#pragma unroll
      for (int r = 0; r < 4; ++r) {
        sA[kf][r] = sA[kf][r] * SC + pv[r];
        sB[kf][r] = sB[kf][r] * SC + pv[r];
      }
    }

    softmax_sub(sA, mA, lA, accA, (char*)pL[w][0], pW);
    softmax_sub(sB, mB, lB, accB, (char*)pL[w][1], pW);

    // O^T += V^T P^T : A=Vt frag (d=16df+lr rows), B=P^T frag
#pragma unroll
    for (int kk = 0; kk < 2; ++kk) {
      const int rdk = kk ? rd1 : rd0;
      const bf16x8 pa = *(const bf16x8*)((const char*)pL[w][0] + rdk);
      const bf16x8 pb = *(const bf16x8*)((const char*)pL[w][1] + rdk);
#pragma unroll
      for (int df = 0; df < 4; ++df) {
        const bf16x8 vf = *(const bf16x8*)((const char*)vT + rdk + df * 2048);
        accA[df] = __builtin_amdgcn_mfma_f32_16x16x32_bf16(vf, pa, accA[df], 0, 0, 0);
        accB[df] = __builtin_amdgcn_mfma_f32_16x16x32_bf16(vf, pb, accB[df], 0, 0, 0);
      }
    }
    __syncthreads();
  }

  const float rlA = __builtin_amdgcn_rcpf(lA);
  const float rlB = __builtin_amdgcn_rcpf(lB);
  unsigned short* Op = O + ((size_t)(b * 2048 + q0 + w * 32 + lr) * 1024 + h * 64);
#pragma unroll
  for (int df = 0; df < 4; ++df) {
    ushort4 oa, ob;
    oa.x = f2b(accA[df][0] * rlA); oa.y = f2b(accA[df][1] * rlA);
    oa.z = f2b(accA[df][2] * rlA); oa.w = f2b(accA[df][3] * rlA);
    ob.x = f2b(accB[df][0] * rlB); ob.y = f2b(accB[df][1] * rlB);
    ob.z = f2b(accB[df][2] * rlB); ob.w = f2b(accB[df][3] * rlB);
    *(ushort4*)(Op + df * 16 + lq * 4) = oa;           // 4 consecutive d, 8B store
    *(ushort4*)(Op + 16384 + df * 16 + lq * 4) = ob;   // subtile B (+16 rows)
  }
}

// ---------------- launch ----------------
extern "C" void kernel_launch(void* const* d_in, const int* in_sizes, int n_in,
                              void* d_out, int out_size, void* d_ws, size_t ws_size,
                              hipStream_t stream) {
  const float* queries = (const float*)d_in[0];
  const float* keys = (const float*)d_in[1];
  const float* values = (const float*)d_in[2];
  const float* presence = (const float*)d_in[3];
  const float* wq = (const float*)d_in[5];
  const float* bq = (const float*)d_in[6];
  const float* wk = (const float*)d_in[7];
  const float* bk = (const float*)d_in[8];
  const float* wv = (const float*)d_in[9];
  const float* bv = (const float*)d_in[10];
  const float* wo = (const float*)d_in[11];
  const float* bo = (const float*)d_in[12];
  float* out = (float*)d_out;

  char* ws = (char*)d_ws;
  unsigned short* inb = (unsigned short*)(ws + (size_t)0);          // 16 MiB
  unsigned short* qb  = (unsigned short*)(ws + (size_t)16777216);   // 16 MiB
  unsigned short* kb  = (unsigned short*)(ws + (size_t)33554432);   // 16 MiB
  unsigned short* vb  = (unsigned short*)(ws + (size_t)50331648);   // 16 MiB
  unsigned short* vTg = (unsigned short*)(ws + (size_t)67108864);   // 16 MiB
  unsigned short* wqT = (unsigned short*)(ws + (size_t)83886080);   // 2 MiB each
  unsigned short* wkT = wqT + 1048576;
  unsigned short* wvT = wkT + 1048576;
  unsigned short* woT = wvT + 1048576;
  float* pmb = (float*)(ws + (size_t)92274688);                     // 32 KiB

  const dim3 wtg(32, 32), wtb(32, 8);
  const dim3 vtg(32, 16, 4);
  const dim3 atg(16, 16, 4);
  const int cvtBlocks = 8192;

  mask_kernel<<<32, 256, 0, stream>>>(presence, pmb, 8192);

  cvt_kernel<<<cvtBlocks, 256, 0, stream>>>(queries, inb, 2097152);
  wtrans_kernel<<<wtg, wtb, 0, stream>>>(wq, wqT);
  gemm_bt_kernel<unsigned short><<<512, 256, 0, stream>>>(inb, wqT, bq, qb, 1024, 1024);

  cvt_kernel<<<cvtBlocks, 256, 0, stream>>>(keys, inb, 2097152);
  wtrans_kernel<<<wtg, wtb, 0, stream>>>(wk, wkT);
  gemm_bt_kernel<unsigned short><<<512, 256, 0, stream>>>(inb, wkT, bk, kb, 1024, 1024);

  cvt_kernel<<<cvtBlocks, 256, 0, stream>>>(values, inb, 2097152);
  wtrans_kernel<<<wtg, wtb, 0, stream>>>(wv, wvT);
  gemm_bt_kernel<unsigned short><<<512, 256, 0, stream>>>(inb, wvT, bv, vb, 1024, 1024);

  vtrans_kernel<<<vtg, 256, 0, stream>>>(vb, vTg);

  attn_kernel<<<atg, 256, 0, stream>>>(qb, kb, vTg, pmb, inb);

  wtrans_kernel<<<wtg, wtb, 0, stream>>>(wo, woT);
  gemm_bt_kernel<float><<<512, 256, 0, stream>>>(inb, woT, bo, out, 1024, 1024);
}

// Round 7
// 385.993 us; speedup vs baseline: 1.3185x; 1.0864x over previous
//
#include <hip/hip_runtime.h>

// MultiHeadQKVAttention: B=4, N=M=2048, DK=DV=DKP=DVP=1024, H=16, dh=dv=64.
// Pipeline: cvt(f32->bf16) -> 3x proj GEMM (bf16 MFMA) -> V transpose ->
// flash attention (swapped-operand, in-register softmax, permlane P-redistribution)
// -> output GEMM.

#define DI __device__ __forceinline__

typedef float f32x4 __attribute__((ext_vector_type(4)));
typedef __bf16 bf16x8 __attribute__((ext_vector_type(8)));
typedef __bf16 bf16x2 __attribute__((ext_vector_type(2)));
typedef unsigned short ushort8v __attribute__((ext_vector_type(8)));
typedef unsigned int uint4v __attribute__((ext_vector_type(4)));

typedef const __attribute__((address_space(1))) void gvoid_t;
typedef __attribute__((address_space(3))) void lvoid_t;

DI unsigned short f2b(float f) { return __builtin_bit_cast(unsigned short, (__bf16)f); }

DI unsigned pack2(float a, float b) {  // -> v_cvt_pk_bf16_f32
  bf16x2 v;
  v[0] = (__bf16)a;
  v[1] = (__bf16)b;
  return __builtin_bit_cast(unsigned, v);
}

DI void swap32(unsigned& x, unsigned& y) {
  asm volatile("v_permlane32_swap_b32 %0, %1" : "+v"(x), "+v"(y));
}
DI void swap16(unsigned& x, unsigned& y) {
  asm volatile("v_permlane16_swap_b32 %0, %1" : "+v"(x), "+v"(y));
}

DI void gload16(const void* g, void* l) {
  __builtin_amdgcn_global_load_lds((gvoid_t*)g, (lvoid_t*)l, 16, 0, 0);
}

// ---------------- f32 -> bf16 convert (vectorized) ----------------
__global__ __launch_bounds__(256) void cvt_kernel(const float* __restrict__ in,
                                                  unsigned short* __restrict__ out, int n4) {
  int i = blockIdx.x * 256 + threadIdx.x;
  if (i < n4) {
    float4 v = ((const float4*)in)[i];
    ushort4 o;
    o.x = f2b(v.x); o.y = f2b(v.y); o.z = f2b(v.z); o.w = f2b(v.w);
    ((ushort4*)out)[i] = o;
  }
}

// ---------------- mask precompute: pm[b][m] = (pres-1)*1e32*0.125*log2e ----------------
__global__ __launch_bounds__(256) void mask_kernel(const float* __restrict__ pres,
                                                   float* __restrict__ pm, int n) {
  int i = blockIdx.x * 256 + threadIdx.x;
  if (i < n) pm[i] = (pres[i] - 1.0f) * 1.8033688011112042e31f;
}

// ---------------- weight transpose+convert: W[K][N] f32 -> Wt[N][K] bf16 ----------------
__global__ __launch_bounds__(256) void wtrans_kernel(const float* __restrict__ in,
                                                     unsigned short* __restrict__ out) {
  __shared__ float t[32][33];
  const int n0 = blockIdx.x * 32, k0 = blockIdx.y * 32;
  const int tx = threadIdx.x, ty = threadIdx.y;
#pragma unroll
  for (int i = 0; i < 4; ++i)
    t[ty + i * 8][tx] = in[(size_t)(k0 + ty + i * 8) * 1024 + n0 + tx];
  __syncthreads();
#pragma unroll
  for (int i = 0; i < 4; ++i)
    out[(size_t)(n0 + ty + i * 8) * 1024 + k0 + tx] = f2b(t[tx][ty + i * 8]);
}

// ---------------- V transpose per head: vb[B][M][H*64] -> vT[B][H][64][M] ----------------
__global__ __launch_bounds__(256) void vtrans_kernel(const unsigned short* __restrict__ vb,
                                                     unsigned short* __restrict__ vTg) {
  __shared__ unsigned short t[64][66];
  const int m0 = blockIdx.x * 64;
  const int h = blockIdx.y, b = blockIdx.z;
  const int tid = (int)threadIdx.x;
#pragma unroll
  for (int i = 0; i < 2; ++i) {
    int idx = i * 256 + tid;
    int row = idx >> 3;
    int d0 = (idx & 7) * 8;
    ushort8v v = *(const ushort8v*)(vb + ((size_t)(b * 2048 + m0 + row) * 16 + h) * 64 + d0);
#pragma unroll
    for (int j = 0; j < 8; ++j) t[row][d0 + j] = v[j];
  }
  __syncthreads();
#pragma unroll
  for (int i = 0; i < 2; ++i) {
    int idx = i * 256 + tid;
    int d = idx >> 3;
    int mo = (idx & 7) * 8;
    ushort8v o;
#pragma unroll
    for (int j = 0; j < 8; ++j) o[j] = t[mo + j][d];
    *(ushort8v*)(vTg + (((size_t)(b * 16 + h) * 64 + d) * 2048 + m0 + mo)) = o;
  }
}

// ---------------- GEMM: C[.][Ng] = A[.][Kg](bf16) @ Bt[Ng][Kg]^T(bf16) + bias ----------------
template <typename CT>
__global__ __launch_bounds__(256, 2) void gemm_bt_kernel(const unsigned short* __restrict__ A,
                                                         const unsigned short* __restrict__ Bt,
                                                         const float* __restrict__ bias,
                                                         CT* __restrict__ C, int Ng, int Kg) {
  __shared__ unsigned short ldsA[128 * 64];
  __shared__ unsigned short ldsB[128 * 64];

  const int nbx = Ng >> 7;
  const int nwg = gridDim.x;
  const int cpx = nwg >> 3;
  const int wg0 = (int)blockIdx.x;
  const int wg = (wg0 & 7) * cpx + (wg0 >> 3);
  const int by = wg / nbx, bx = wg % nbx;

  const int tid = (int)threadIdx.x;
  const int w = tid >> 6, lane = tid & 63;
  const int lq = lane >> 4, lr = lane & 15;
  const int wr = w >> 1, wc = w & 1;

  const size_t rowA = (size_t)by * 128;
  const int colB = bx * 128;

  f32x4 acc[4][4];
#pragma unroll
  for (int m = 0; m < 4; ++m)
#pragma unroll
    for (int n = 0; n < 4; ++n) acc[m][n] = f32x4{0.f, 0.f, 0.f, 0.f};

  for (int k0 = 0; k0 < Kg; k0 += 64) {
#pragma unroll
    for (int i = 0; i < 4; ++i) {
      const int c = w * 4 + i;
      const int off = c * 1024 + lane * 16;
      const int row = off >> 7;
      const int kbs = (off & 127) ^ ((row & 7) << 4);
      gload16(A + ((rowA + row) * (size_t)Kg + k0 + (kbs >> 1)), &ldsA[c * 512]);
      gload16(Bt + ((size_t)(colB + row) * Kg + k0 + (kbs >> 1)), &ldsB[c * 512]);
    }
    __syncthreads();
#pragma unroll
    for (int kk = 0; kk < 2; ++kk) {
      const int kbyte = kk * 64 + lq * 16;
      bf16x8 af[4], bfv[4];
#pragma unroll
      for (int m = 0; m < 4; ++m) {
        const int row = wr * 64 + m * 16 + lr;
        af[m] = *(const bf16x8*)((const char*)ldsA + row * 128 + (kbyte ^ ((row & 7) << 4)));
      }
#pragma unroll
      for (int n = 0; n < 4; ++n) {
        const int row = wc * 64 + n * 16 + lr;
        bfv[n] = *(const bf16x8*)((const char*)ldsB + row * 128 + (kbyte ^ ((row & 7) << 4)));
      }
#pragma unroll
      for (int m = 0; m < 4; ++m)
#pragma unroll
        for (int n = 0; n < 4; ++n)
          acc[m][n] = __builtin_amdgcn_mfma_f32_16x16x32_bf16(af[m], bfv[n], acc[m][n], 0, 0, 0);
    }
    __syncthreads();
  }

#pragma unroll
  for (int n = 0; n < 4; ++n) {
    const int col = colB + wc * 64 + n * 16 + lr;
    const float bvl = bias[col];
#pragma unroll
    for (int m = 0; m < 4; ++m) {
      const size_t r0 = rowA + wr * 64 + m * 16 + lq * 4;
#pragma unroll
      for (int r = 0; r < 4; ++r) {
        const float v = acc[m][n][r] + bvl;
        if constexpr (sizeof(CT) == 2)
          C[(r0 + r) * Ng + col] = f2b(v);
        else
          C[(r0 + r) * Ng + col] = v;
      }
    }
  }
}

// ---------------- Flash attention (swapped operands, in-register softmax + permlane) --------
// Block = 4 waves, 128 q-rows (2 subtiles of 16 per wave), KVBLK=64, dh=dv=64.
// QK^T swapped: S^T[key][q] = mfma(A=Kfrag, B=Qfrag) -> lane owns q=lr, keys 16kf+4lq+r.
// P redistribution to PV B-frag fully in-register:
//   word w of frag(kc) = pk[2kc+(lq>>1)][w&1] @ srclane 32(lq&1)+16(w>>1)+lr
//   = permlane16_swap(permlane32_swap(X=pk[2kc][c], Y=pk[2kc+1][c])) -> (w_c, w_{c+2}).
// PV swapped: O^T[d][q] = mfma(A=Vtfrag, B=P^Tfrag) -> lane owns q=lr, d=16df+4lq+r.
DI void softmax_pk(f32x4 s[4], float& mrun, float& lrun, f32x4 acc[4], unsigned* pk) {
  float rm = fmaxf(fmaxf(s[0][0], s[0][1]), fmaxf(s[0][2], s[0][3]));
#pragma unroll
  for (int kf = 1; kf < 4; ++kf)
    rm = fmaxf(rm, fmaxf(fmaxf(s[kf][0], s[kf][1]), fmaxf(s[kf][2], s[kf][3])));
  rm = fmaxf(rm, __shfl_xor(rm, 16, 64));
  rm = fmaxf(rm, __shfl_xor(rm, 32, 64));
  if (__any(rm > mrun + 8.0f)) {  // defer-max (T13): only rescale on real growth
    const float mn = fmaxf(mrun, rm);
    const float al = __builtin_amdgcn_exp2f(mrun - mn);
    lrun *= al;
#pragma unroll
    for (int df = 0; df < 4; ++df) acc[df] *= al;
    mrun = mn;
  }
  float rs = 0.f;
#pragma unroll
  for (int kf = 0; kf < 4; ++kf) {
#pragma unroll
    for (int r = 0; r < 4; ++r) {
      const float p = __builtin_amdgcn_exp2f(s[kf][r] - mrun);  // raw v_exp_f32
      s[kf][r] = p;
      rs += p;
    }
    pk[kf * 2] = pack2(s[kf][0], s[kf][1]);
    pk[kf * 2 + 1] = pack2(s[kf][2], s[kf][3]);
  }
  rs += __shfl_xor(rs, 16, 64);
  rs += __shfl_xor(rs, 32, 64);
  lrun += rs;
}

DI bf16x8 pv_frag(const unsigned* pk, int kc) {
  unsigned x0 = pk[4 * kc + 0], y0 = pk[4 * kc + 2];
  swap32(x0, y0);
  swap16(x0, y0);  // x0 = word0, y0 = word2
  unsigned x1 = pk[4 * kc + 1], y1 = pk[4 * kc + 3];
  swap32(x1, y1);
  swap16(x1, y1);  // x1 = word1, y1 = word3
  uint4v wds;
  wds[0] = x0; wds[1] = x1; wds[2] = y0; wds[3] = y1;
  return __builtin_bit_cast(bf16x8, wds);
}

__global__ __launch_bounds__(256, 4) void attn_kernel(const unsigned short* __restrict__ Q,
                                                      const unsigned short* __restrict__ K,
                                                      const unsigned short* __restrict__ Vt,
                                                      const float* __restrict__ pm,
                                                      unsigned short* __restrict__ O) {
  __shared__ unsigned short kT[64 * 64];  // [key][d] swizzled (8KB)
  __shared__ unsigned short vT[64 * 64];  // [d][key] swizzled (8KB)

  const int q0 = blockIdx.x * 128;
  const int h = blockIdx.y, b = blockIdx.z;
  const int tid = (int)threadIdx.x;
  const int w = tid >> 6, lane = tid & 63;
  const int lq = lane >> 4, lr = lane & 15;

  // Q fragments (B-operand): col=q=lr, k = kk*32 + lq*8 .. +7
  const unsigned short* qp = Q + ((size_t)(b * 2048 + q0 + w * 32 + lr) * 1024 + h * 64);
  const bf16x8 qfA0 = *(const bf16x8*)(qp + lq * 8);
  const bf16x8 qfA1 = *(const bf16x8*)(qp + 32 + lq * 8);
  const bf16x8 qfB0 = *(const bf16x8*)(qp + 16384 + lq * 8);
  const bf16x8 qfB1 = *(const bf16x8*)(qp + 16384 + 32 + lq * 8);

  // per-lane LDS byte offsets (loop-invariant)
  const int s7 = (lr & 7) << 4;
  const int rd0 = lr * 128 + ((lq * 16) ^ s7);       // kk=0 frag read (K/V)
  const int rd1 = lr * 128 + ((64 + lq * 16) ^ s7);  // kk=1

  // staging: chunks c = w*2 + {0,1}; row = c*8 + lane/8, col = (lane&7)*16 inv-swizzled
  const int rowS0 = w * 16 + (lane >> 3), rowS1 = rowS0 + 8;
  const int colS0 = ((lane & 7) * 16) ^ ((rowS0 & 7) << 4);
  const int colS1 = ((lane & 7) * 16) ^ ((rowS1 & 7) << 4);
  const unsigned short* Kb = K + (size_t)(b * 2048) * 1024 + h * 64;
  const unsigned short* Vb = Vt + (size_t)((b * 16 + h) * 64) * 2048;
  const float* pmB = pm + b * 2048;

  f32x4 accA[4], accB[4];
#pragma unroll
  for (int df = 0; df < 4; ++df) {
    accA[df] = f32x4{0.f, 0.f, 0.f, 0.f};
    accB[df] = f32x4{0.f, 0.f, 0.f, 0.f};
  }
  float mA = -3.0e38f, lA = 0.f, mB = -3.0e38f, lB = 0.f;

  for (int m0 = 0; m0 < 2048; m0 += 64) {
    gload16(Kb + (size_t)(m0 + rowS0) * 1024 + (colS0 >> 1), &kT[(w * 2) * 512]);
    gload16(Vb + (size_t)rowS0 * 2048 + m0 + (colS0 >> 1), &vT[(w * 2) * 512]);
    gload16(Kb + (size_t)(m0 + rowS1) * 1024 + (colS1 >> 1), &kT[(w * 2 + 1) * 512]);
    gload16(Vb + (size_t)rowS1 * 2048 + m0 + (colS1 >> 1), &vT[(w * 2 + 1) * 512]);
    __syncthreads();

    // S^T = K Q^T : s[kf] holds keys 16kf+4lq+r for q=lr
    f32x4 sA[4], sB[4];
#pragma unroll
    for (int kf = 0; kf < 4; ++kf) {
      sA[kf] = f32x4{0.f, 0.f, 0.f, 0.f};
      sB[kf] = f32x4{0.f, 0.f, 0.f, 0.f};
    }
#pragma unroll
    for (int kk = 0; kk < 2; ++kk) {
      const int rdk = kk ? rd1 : rd0;
      const bf16x8 qa = kk ? qfA1 : qfA0;
      const bf16x8 qb = kk ? qfB1 : qfB0;
#pragma unroll
      for (int kf = 0; kf < 4; ++kf) {
        const bf16x8 kfr = *(const bf16x8*)((const char*)kT + rdk + kf * 2048);
        sA[kf] = __builtin_amdgcn_mfma_f32_16x16x32_bf16(kfr, qa, sA[kf], 0, 0, 0);
        sB[kf] = __builtin_amdgcn_mfma_f32_16x16x32_bf16(kfr, qb, sB[kf], 0, 0, 0);
      }
    }

    // scale to log2 domain + additive mask (pre-scaled): one fma per element
    const float SC = 0.18033688011112042f;  // 0.125 * log2(e)
#pragma unroll
    for (int kf = 0; kf < 4; ++kf) {
      const f32x4 pv = *(const f32x4*)(pmB + m0 + kf * 16 + lq * 4);
#pragma unroll
      for (int r = 0; r < 4; ++r) {
        sA[kf][r] = sA[kf][r] * SC + pv[r];
        sB[kf][r] = sB[kf][r] * SC + pv[r];
      }
    }

    unsigned pkA[8], pkB[8];
    softmax_pk(sA, mA, lA, accA, pkA);
    softmax_pk(sB, mB, lB, accB, pkB);

    // O^T += V^T P^T : A=Vt frag (d=16df+lr rows), B=P^T frag from permlane redistribution
#pragma unroll
    for (int kc = 0; kc < 2; ++kc) {
      const int rdk = kc ? rd1 : rd0;
      const bf16x8 pa = pv_frag(pkA, kc);
      const bf16x8 pb = pv_frag(pkB, kc);
#pragma unroll
      for (int df = 0; df < 4; ++df) {
        const bf16x8 vf = *(const bf16x8*)((const char*)vT + rdk + df * 2048);
        accA[df] = __builtin_amdgcn_mfma_f32_16x16x32_bf16(vf, pa, accA[df], 0, 0, 0);
        accB[df] = __builtin_amdgcn_mfma_f32_16x16x32_bf16(vf, pb, accB[df], 0, 0, 0);
      }
    }
    __syncthreads();
  }

  const float rlA = __builtin_amdgcn_rcpf(lA);
  const float rlB = __builtin_amdgcn_rcpf(lB);
  unsigned short* Op = O + ((size_t)(b * 2048 + q0 + w * 32 + lr) * 1024 + h * 64);
#pragma unroll
  for (int df = 0; df < 4; ++df) {
    ushort4 oa, ob;
    oa.x = f2b(accA[df][0] * rlA); oa.y = f2b(accA[df][1] * rlA);
    oa.z = f2b(accA[df][2] * rlA); oa.w = f2b(accA[df][3] * rlA);
    ob.x = f2b(accB[df][0] * rlB); ob.y = f2b(accB[df][1] * rlB);
    ob.z = f2b(accB[df][2] * rlB); ob.w = f2b(accB[df][3] * rlB);
    *(ushort4*)(Op + df * 16 + lq * 4) = oa;          // 4 consecutive d, 8B store
    *(ushort4*)(Op + 16384 + df * 16 + lq * 4) = ob;  // subtile B (+16 rows)
  }
}

// ---------------- launch ----------------
extern "C" void kernel_launch(void* const* d_in, const int* in_sizes, int n_in,
                              void* d_out, int out_size, void* d_ws, size_t ws_size,
                              hipStream_t stream) {
  const float* queries = (const float*)d_in[0];
  const float* keys = (const float*)d_in[1];
  const float* values = (const float*)d_in[2];
  const float* presence = (const float*)d_in[3];
  const float* wq = (const float*)d_in[5];
  const float* bq = (const float*)d_in[6];
  const float* wk = (const float*)d_in[7];
  const float* bk = (const float*)d_in[8];
  const float* wv = (const float*)d_in[9];
  const float* bv = (const float*)d_in[10];
  const float* wo = (const float*)d_in[11];
  const float* bo = (const float*)d_in[12];
  float* out = (float*)d_out;

  char* ws = (char*)d_ws;
  unsigned short* inb = (unsigned short*)(ws + (size_t)0);         // 16 MiB
  unsigned short* qb = (unsigned short*)(ws + (size_t)16777216);   // 16 MiB
  unsigned short* kb = (unsigned short*)(ws + (size_t)33554432);   // 16 MiB
  unsigned short* vb = (unsigned short*)(ws + (size_t)50331648);   // 16 MiB
  unsigned short* vTg = (unsigned short*)(ws + (size_t)67108864);  // 16 MiB
  unsigned short* wqT = (unsigned short*)(ws + (size_t)83886080);  // 2 MiB each
  unsigned short* wkT = wqT + 1048576;
  unsigned short* wvT = wkT + 1048576;
  unsigned short* woT = wvT + 1048576;
  float* pmb = (float*)(ws + (size_t)92274688);  // 32 KiB

  const dim3 wtg(32, 32), wtb(32, 8);
  const dim3 vtg(32, 16, 4);
  const dim3 atg(16, 16, 4);
  const int cvtBlocks = 8192;

  mask_kernel<<<32, 256, 0, stream>>>(presence, pmb, 8192);

  cvt_kernel<<<cvtBlocks, 256, 0, stream>>>(queries, inb, 2097152);
  wtrans_kernel<<<wtg, wtb, 0, stream>>>(wq, wqT);
  gemm_bt_kernel<unsigned short><<<512, 256, 0, stream>>>(inb, wqT, bq, qb, 1024, 1024);

  cvt_kernel<<<cvtBlocks, 256, 0, stream>>>(keys, inb, 2097152);
  wtrans_kernel<<<wtg, wtb, 0, stream>>>(wk, wkT);
  gemm_bt_kernel<unsigned short><<<512, 256, 0, stream>>>(inb, wkT, bk, kb, 1024, 1024);

  cvt_kernel<<<cvtBlocks, 256, 0, stream>>>(values, inb, 2097152);
  wtrans_kernel<<<wtg, wtb, 0, stream>>>(wv, wvT);
  gemm_bt_kernel<unsigned short><<<512, 256, 0, stream>>>(inb, wvT, bv, vb, 1024, 1024);

  vtrans_kernel<<<vtg, 256, 0, stream>>>(vb, vTg);

  attn_kernel<<<atg, 256, 0, stream>>>(qb, kb, vTg, pmb, inb);

  wtrans_kernel<<<wtg, wtb, 0, stream>>>(wo, woT);
  gemm_bt_kernel<float><<<512, 256, 0, stream>>>(inb, woT, bo, out, 1024, 1024);
}

// Round 10
// 374.744 us; speedup vs baseline: 1.3580x; 1.0300x over previous
//
#include <hip/hip_runtime.h>

// MultiHeadQKVAttention: B=4, N=M=2048, DK=DV=DKP=DVP=1024, H=16, dh=dv=64.
// 6-launch pipeline: mask -> cvt3(f32->bf16) -> wtrans4 -> batched QKV GEMM
// (V written pre-transposed) -> flash attention -> output GEMM.

#define DI __device__ __forceinline__

typedef float f32x4 __attribute__((ext_vector_type(4)));
typedef __bf16 bf16x8 __attribute__((ext_vector_type(8)));
typedef __bf16 bf16x2 __attribute__((ext_vector_type(2)));
typedef unsigned short ushort8v __attribute__((ext_vector_type(8)));
typedef unsigned int uint4v __attribute__((ext_vector_type(4)));

typedef const __attribute__((address_space(1))) void gvoid_t;
typedef __attribute__((address_space(3))) void lvoid_t;

DI unsigned short f2b(float f) { return __builtin_bit_cast(unsigned short, (__bf16)f); }

DI unsigned pack2(float a, float b) {  // -> v_cvt_pk_bf16_f32
  bf16x2 v;
  v[0] = (__bf16)a;
  v[1] = (__bf16)b;
  return __builtin_bit_cast(unsigned, v);
}

DI void swap32(unsigned& x, unsigned& y) {
  asm volatile("v_permlane32_swap_b32 %0, %1" : "+v"(x), "+v"(y));
}
DI void swap16(unsigned& x, unsigned& y) {
  asm volatile("v_permlane16_swap_b32 %0, %1" : "+v"(x), "+v"(y));
}

DI void gload16(const void* g, void* l) {
  __builtin_amdgcn_global_load_lds((gvoid_t*)g, (lvoid_t*)l, 16, 0, 0);
}

// ---------------- batched f32 -> bf16 convert: z selects tensor ----------------
__global__ __launch_bounds__(256) void cvt3_kernel(const float* __restrict__ q,
                                                   const float* __restrict__ k,
                                                   const float* __restrict__ v,
                                                   unsigned short* __restrict__ qo,
                                                   unsigned short* __restrict__ ko,
                                                   unsigned short* __restrict__ vo) {
  const int z = blockIdx.y;
  const float* in = z == 0 ? q : z == 1 ? k : v;
  unsigned short* out = z == 0 ? qo : z == 1 ? ko : vo;
  int i = blockIdx.x * 256 + threadIdx.x;  // 2097152 float4s per tensor
  float4 vv = ((const float4*)in)[i];
  ushort4 o;
  o.x = f2b(vv.x); o.y = f2b(vv.y); o.z = f2b(vv.z); o.w = f2b(vv.w);
  ((ushort4*)out)[i] = o;
}

// ---------------- mask precompute: pm[b][m] = (pres-1)*1e32*0.125*log2e ----------------
__global__ __launch_bounds__(256) void mask_kernel(const float* __restrict__ pres,
                                                   float* __restrict__ pm, int n) {
  int i = blockIdx.x * 256 + threadIdx.x;
  if (i < n) pm[i] = (pres[i] - 1.0f) * 1.8033688011112042e31f;
}

// ---------------- batched weight transpose: W[K][N] f32 -> Wt[N][K] bf16, z=4 ----------------
__global__ __launch_bounds__(256) void wtrans4_kernel(const float* __restrict__ w0,
                                                      const float* __restrict__ w1,
                                                      const float* __restrict__ w2,
                                                      const float* __restrict__ w3,
                                                      unsigned short* __restrict__ o0,
                                                      unsigned short* __restrict__ o1,
                                                      unsigned short* __restrict__ o2,
                                                      unsigned short* __restrict__ o3) {
  __shared__ float t[32][33];
  const int z = blockIdx.z;
  const float* in = z == 0 ? w0 : z == 1 ? w1 : z == 2 ? w2 : w3;
  unsigned short* out = z == 0 ? o0 : z == 1 ? o1 : z == 2 ? o2 : o3;
  const int n0 = blockIdx.x * 32, k0 = blockIdx.y * 32;
  const int tx = threadIdx.x, ty = threadIdx.y;
#pragma unroll
  for (int i = 0; i < 4; ++i)
    t[ty + i * 8][tx] = in[(size_t)(k0 + ty + i * 8) * 1024 + n0 + tx];
  __syncthreads();
#pragma unroll
  for (int i = 0; i < 4; ++i)
    out[(size_t)(n0 + ty + i * 8) * 1024 + k0 + tx] = f2b(t[tx][ty + i * 8]);
}

// ---------------- GEMM core ----------------
// 128x128 tile, BK=64, 4 waves (2x2), 16x16x32 bf16 MFMA, XOR swizzle family:
// linear global_load_lds dest + inverse-swizzled global source + swizzled ds_read.

// Batched QKV projection GEMM. z=0: qb, z=1: kb, z=2: V -> vTg pre-transposed.
__global__ __launch_bounds__(256, 3) void gemm_qkv_kernel(
    const unsigned short* __restrict__ qin, const unsigned short* __restrict__ kin,
    const unsigned short* __restrict__ vin, const unsigned short* __restrict__ wqT,
    const unsigned short* __restrict__ wkT, const unsigned short* __restrict__ wvT,
    const float* __restrict__ bq, const float* __restrict__ bk,
    const float* __restrict__ bv, unsigned short* __restrict__ qb,
    unsigned short* __restrict__ kb, unsigned short* __restrict__ vTg) {
  __shared__ unsigned short ldsA[128 * 64];
  __shared__ unsigned short ldsB[128 * 64];

  const int z = blockIdx.z;
  const unsigned short* A = z == 0 ? qin : z == 1 ? kin : vin;
  const unsigned short* Bt = z == 0 ? wqT : z == 1 ? wkT : wvT;
  const float* bias = z == 0 ? bq : z == 1 ? bk : bv;

  const int nbx = 8;  // Ng=1024
  const int cpx = 64; // 512 blocks / 8 XCDs
  const int wg0 = (int)blockIdx.x;
  const int wg = (wg0 & 7) * cpx + (wg0 >> 3);
  const int by = wg / nbx, bx = wg % nbx;

  const int tid = (int)threadIdx.x;
  const int w = tid >> 6, lane = tid & 63;
  const int lq = lane >> 4, lr = lane & 15;
  const int wr = w >> 1, wc = w & 1;

  const size_t rowA = (size_t)by * 128;
  const int colB = bx * 128;

  f32x4 acc[4][4];
#pragma unroll
  for (int m = 0; m < 4; ++m)
#pragma unroll
    for (int n = 0; n < 4; ++n) acc[m][n] = f32x4{0.f, 0.f, 0.f, 0.f};

  for (int k0 = 0; k0 < 1024; k0 += 64) {
#pragma unroll
    for (int i = 0; i < 4; ++i) {
      const int c = w * 4 + i;
      const int off = c * 1024 + lane * 16;
      const int row = off >> 7;
      const int kbs = (off & 127) ^ ((row & 7) << 4);
      gload16(A + ((rowA + row) * 1024 + k0 + (kbs >> 1)), &ldsA[c * 512]);
      gload16(Bt + ((size_t)(colB + row) * 1024 + k0 + (kbs >> 1)), &ldsB[c * 512]);
    }
    __syncthreads();
#pragma unroll
    for (int kk = 0; kk < 2; ++kk) {
      const int kbyte = kk * 64 + lq * 16;
      bf16x8 af[4], bfv[4];
#pragma unroll
      for (int m = 0; m < 4; ++m) {
        const int row = wr * 64 + m * 16 + lr;
        af[m] = *(const bf16x8*)((const char*)ldsA + row * 128 + (kbyte ^ ((row & 7) << 4)));
      }
#pragma unroll
      for (int n = 0; n < 4; ++n) {
        const int row = wc * 64 + n * 16 + lr;
        bfv[n] = *(const bf16x8*)((const char*)ldsB + row * 128 + (kbyte ^ ((row & 7) << 4)));
      }
#pragma unroll
      for (int m = 0; m < 4; ++m)
#pragma unroll
        for (int n = 0; n < 4; ++n)
          acc[m][n] = __builtin_amdgcn_mfma_f32_16x16x32_bf16(af[m], bfv[n], acc[m][n], 0, 0, 0);
    }
    __syncthreads();
  }

  if (z < 2) {
    unsigned short* C = z == 0 ? qb : kb;
#pragma unroll
    for (int n = 0; n < 4; ++n) {
      const int col = colB + wc * 64 + n * 16 + lr;
      const float bvl = bias[col];
#pragma unroll
      for (int m = 0; m < 4; ++m) {
        const size_t r0 = rowA + wr * 64 + m * 16 + lq * 4;
#pragma unroll
        for (int r = 0; r < 4; ++r) C[(r0 + r) * 1024 + col] = f2b(acc[m][n][r] + bvl);
      }
    }
  } else {
    // V: write transposed vTg[(b*16+h)*64+d][ml] = [b*1024+col][ml], 4 consecutive ml
#pragma unroll
    for (int n = 0; n < 4; ++n) {
      const int col = colB + wc * 64 + n * 16 + lr;  // h*64+d
      const float bvl = bias[col];
#pragma unroll
      for (int m = 0; m < 4; ++m) {
        const size_t row0 = rowA + wr * 64 + m * 16 + lq * 4;  // global m index
        const int bb = (int)(row0 >> 11);
        const int ml = (int)(row0 & 2047);
        ushort4 o;
        o.x = f2b(acc[m][n][0] + bvl);
        o.y = f2b(acc[m][n][1] + bvl);
        o.z = f2b(acc[m][n][2] + bvl);
        o.w = f2b(acc[m][n][3] + bvl);
        *(ushort4*)(vTg + (((size_t)(bb * 1024 + col)) << 11) + ml) = o;
      }
    }
  }
}

// ---------------- output GEMM: C[.][1024] f32 = A @ Bt^T + bias ----------------
__global__ __launch_bounds__(256, 3) void gemm_bt_kernel(const unsigned short* __restrict__ A,
                                                         const unsigned short* __restrict__ Bt,
                                                         const float* __restrict__ bias,
                                                         float* __restrict__ C) {
  __shared__ unsigned short ldsA[128 * 64];
  __shared__ unsigned short ldsB[128 * 64];

  const int nbx = 8;
  const int cpx = 64;
  const int wg0 = (int)blockIdx.x;
  const int wg = (wg0 & 7) * cpx + (wg0 >> 3);
  const int by = wg / nbx, bx = wg % nbx;

  const int tid = (int)threadIdx.x;
  const int w = tid >> 6, lane = tid & 63;
  const int lq = lane >> 4, lr = lane & 15;
  const int wr = w >> 1, wc = w & 1;

  const size_t rowA = (size_t)by * 128;
  const int colB = bx * 128;

  f32x4 acc[4][4];
#pragma unroll
  for (int m = 0; m < 4; ++m)
#pragma unroll
    for (int n = 0; n < 4; ++n) acc[m][n] = f32x4{0.f, 0.f, 0.f, 0.f};

  for (int k0 = 0; k0 < 1024; k0 += 64) {
#pragma unroll
    for (int i = 0; i < 4; ++i) {
      const int c = w * 4 + i;
      const int off = c * 1024 + lane * 16;
      const int row = off >> 7;
      const int kbs = (off & 127) ^ ((row & 7) << 4);
      gload16(A + ((rowA + row) * 1024 + k0 + (kbs >> 1)), &ldsA[c * 512]);
      gload16(Bt + ((size_t)(colB + row) * 1024 + k0 + (kbs >> 1)), &ldsB[c * 512]);
    }
    __syncthreads();
#pragma unroll
    for (int kk = 0; kk < 2; ++kk) {
      const int kbyte = kk * 64 + lq * 16;
      bf16x8 af[4], bfv[4];
#pragma unroll
      for (int m = 0; m < 4; ++m) {
        const int row = wr * 64 + m * 16 + lr;
        af[m] = *(const bf16x8*)((const char*)ldsA + row * 128 + (kbyte ^ ((row & 7) << 4)));
      }
#pragma unroll
      for (int n = 0; n < 4; ++n) {
        const int row = wc * 64 + n * 16 + lr;
        bfv[n] = *(const bf16x8*)((const char*)ldsB + row * 128 + (kbyte ^ ((row & 7) << 4)));
      }
#pragma unroll
      for (int m = 0; m < 4; ++m)
#pragma unroll
        for (int n = 0; n < 4; ++n)
          acc[m][n] = __builtin_amdgcn_mfma_f32_16x16x32_bf16(af[m], bfv[n], acc[m][n], 0, 0, 0);
    }
    __syncthreads();
  }

#pragma unroll
  for (int n = 0; n < 4; ++n) {
    const int col = colB + wc * 64 + n * 16 + lr;
    const float bvl = bias[col];
#pragma unroll
    for (int m = 0; m < 4; ++m) {
      const size_t r0 = rowA + wr * 64 + m * 16 + lq * 4;
#pragma unroll
      for (int r = 0; r < 4; ++r) C[(r0 + r) * 1024 + col] = acc[m][n][r] + bvl;
    }
  }
}

// ---------------- Flash attention (swapped operands, in-register softmax + permlane) --------
DI void softmax_pk(f32x4 s[4], float& mrun, float& lrun, f32x4 acc[4], unsigned* pk) {
  float rm = fmaxf(fmaxf(s[0][0], s[0][1]), fmaxf(s[0][2], s[0][3]));
#pragma unroll
  for (int kf = 1; kf < 4; ++kf)
    rm = fmaxf(rm, fmaxf(fmaxf(s[kf][0], s[kf][1]), fmaxf(s[kf][2], s[kf][3])));
  rm = fmaxf(rm, __shfl_xor(rm, 16, 64));
  rm = fmaxf(rm, __shfl_xor(rm, 32, 64));
  if (__any(rm > mrun + 8.0f)) {  // defer-max (T13)
    const float mn = fmaxf(mrun, rm);
    const float al = __builtin_amdgcn_exp2f(mrun - mn);
    lrun *= al;
#pragma unroll
    for (int df = 0; df < 4; ++df) acc[df] *= al;
    mrun = mn;
  }
  float rs = 0.f;
#pragma unroll
  for (int kf = 0; kf < 4; ++kf) {
#pragma unroll
    for (int r = 0; r < 4; ++r) {
      const float p = __builtin_amdgcn_exp2f(s[kf][r] - mrun);
      s[kf][r] = p;
      rs += p;
    }
    pk[kf * 2] = pack2(s[kf][0], s[kf][1]);
    pk[kf * 2 + 1] = pack2(s[kf][2], s[kf][3]);
  }
  rs += __shfl_xor(rs, 16, 64);
  rs += __shfl_xor(rs, 32, 64);
  lrun += rs;
}

DI bf16x8 pv_frag(const unsigned* pk, int kc) {
  unsigned x0 = pk[4 * kc + 0], y0 = pk[4 * kc + 2];
  swap32(x0, y0);
  swap16(x0, y0);
  unsigned x1 = pk[4 * kc + 1], y1 = pk[4 * kc + 3];
  swap32(x1, y1);
  swap16(x1, y1);
  uint4v wds;
  wds[0] = x0; wds[1] = x1; wds[2] = y0; wds[3] = y1;
  return __builtin_bit_cast(bf16x8, wds);
}

__global__ __launch_bounds__(256, 4) void attn_kernel(const unsigned short* __restrict__ Q,
                                                      const unsigned short* __restrict__ K,
                                                      const unsigned short* __restrict__ Vt,
                                                      const float* __restrict__ pm,
                                                      unsigned short* __restrict__ O) {
  __shared__ unsigned short kT[64 * 64];
  __shared__ unsigned short vT[64 * 64];

  const int q0 = blockIdx.x * 128;
  const int h = blockIdx.y, b = blockIdx.z;
  const int tid = (int)threadIdx.x;
  const int w = tid >> 6, lane = tid & 63;
  const int lq = lane >> 4, lr = lane & 15;

  const unsigned short* qp = Q + ((size_t)(b * 2048 + q0 + w * 32 + lr) * 1024 + h * 64);
  const bf16x8 qfA0 = *(const bf16x8*)(qp + lq * 8);
  const bf16x8 qfA1 = *(const bf16x8*)(qp + 32 + lq * 8);
  const bf16x8 qfB0 = *(const bf16x8*)(qp + 16384 + lq * 8);
  const bf16x8 qfB1 = *(const bf16x8*)(qp + 16384 + 32 + lq * 8);

  const int s7 = (lr & 7) << 4;
  const int rd0 = lr * 128 + ((lq * 16) ^ s7);
  const int rd1 = lr * 128 + ((64 + lq * 16) ^ s7);

  const int rowS0 = w * 16 + (lane >> 3), rowS1 = rowS0 + 8;
  const int colS0 = ((lane & 7) * 16) ^ ((rowS0 & 7) << 4);
  const int colS1 = ((lane & 7) * 16) ^ ((rowS1 & 7) << 4);
  const unsigned short* Kb = K + (size_t)(b * 2048) * 1024 + h * 64;
  const unsigned short* Vb = Vt + (size_t)((b * 16 + h) * 64) * 2048;
  const float* pmB = pm + b * 2048;

  f32x4 accA[4], accB[4];
#pragma unroll
  for (int df = 0; df < 4; ++df) {
    accA[df] = f32x4{0.f, 0.f, 0.f, 0.f};
    accB[df] = f32x4{0.f, 0.f, 0.f, 0.f};
  }
  float mA = -3.0e38f, lA = 0.f, mB = -3.0e38f, lB = 0.f;

  for (int m0 = 0; m0 < 2048; m0 += 64) {
    gload16(Kb + (size_t)(m0 + rowS0) * 1024 + (colS0 >> 1), &kT[(w * 2) * 512]);
    gload16(Vb + (size_t)rowS0 * 2048 + m0 + (colS0 >> 1), &vT[(w * 2) * 512]);
    gload16(Kb + (size_t)(m0 + rowS1) * 1024 + (colS1 >> 1), &kT[(w * 2 + 1) * 512]);
    gload16(Vb + (size_t)rowS1 * 2048 + m0 + (colS1 >> 1), &vT[(w * 2 + 1) * 512]);
    __syncthreads();

    f32x4 sA[4], sB[4];
#pragma unroll
    for (int kf = 0; kf < 4; ++kf) {
      sA[kf] = f32x4{0.f, 0.f, 0.f, 0.f};
      sB[kf] = f32x4{0.f, 0.f, 0.f, 0.f};
    }
#pragma unroll
    for (int kk = 0; kk < 2; ++kk) {
      const int rdk = kk ? rd1 : rd0;
      const bf16x8 qa = kk ? qfA1 : qfA0;
      const bf16x8 qb_ = kk ? qfB1 : qfB0;
#pragma unroll
      for (int kf = 0; kf < 4; ++kf) {
        const bf16x8 kfr = *(const bf16x8*)((const char*)kT + rdk + kf * 2048);
        sA[kf] = __builtin_amdgcn_mfma_f32_16x16x32_bf16(kfr, qa, sA[kf], 0, 0, 0);
        sB[kf] = __builtin_amdgcn_mfma_f32_16x16x32_bf16(kfr, qb_, sB[kf], 0, 0, 0);
      }
    }

    const float SC = 0.18033688011112042f;  // 0.125 * log2(e)
#pragma unroll
    for (int kf = 0; kf < 4; ++kf) {
      const f32x4 pv = *(const f32x4*)(pmB + m0 + kf * 16 + lq * 4);
#pragma unroll
      for (int r = 0; r < 4; ++r) {
        sA[kf][r] = sA[kf][r] * SC + pv[r];
        sB[kf][r] = sB[kf][r] * SC + pv[r];
      }
    }

    unsigned pkA[8], pkB[8];
    softmax_pk(sA, mA, lA, accA, pkA);
    softmax_pk(sB, mB, lB, accB, pkB);

#pragma unroll
    for (int kc = 0; kc < 2; ++kc) {
      const int rdk = kc ? rd1 : rd0;
      const bf16x8 pa = pv_frag(pkA, kc);
      const bf16x8 pb = pv_frag(pkB, kc);
#pragma unroll
      for (int df = 0; df < 4; ++df) {
        const bf16x8 vf = *(const bf16x8*)((const char*)vT + rdk + df * 2048);
        accA[df] = __builtin_amdgcn_mfma_f32_16x16x32_bf16(vf, pa, accA[df], 0, 0, 0);
        accB[df] = __builtin_amdgcn_mfma_f32_16x16x32_bf16(vf, pb, accB[df], 0, 0, 0);
      }
    }
    __syncthreads();
  }

  const float rlA = __builtin_amdgcn_rcpf(lA);
  const float rlB = __builtin_amdgcn_rcpf(lB);
  unsigned short* Op = O + ((size_t)(b * 2048 + q0 + w * 32 + lr) * 1024 + h * 64);
#pragma unroll
  for (int df = 0; df < 4; ++df) {
    ushort4 oa, ob;
    oa.x = f2b(accA[df][0] * rlA); oa.y = f2b(accA[df][1] * rlA);
    oa.z = f2b(accA[df][2] * rlA); oa.w = f2b(accA[df][3] * rlA);
    ob.x = f2b(accB[df][0] * rlB); ob.y = f2b(accB[df][1] * rlB);
    ob.z = f2b(accB[df][2] * rlB); ob.w = f2b(accB[df][3] * rlB);
    *(ushort4*)(Op + df * 16 + lq * 4) = oa;
    *(ushort4*)(Op + 16384 + df * 16 + lq * 4) = ob;
  }
}

// ---------------- launch ----------------
extern "C" void kernel_launch(void* const* d_in, const int* in_sizes, int n_in,
                              void* d_out, int out_size, void* d_ws, size_t ws_size,
                              hipStream_t stream) {
  const float* queries = (const float*)d_in[0];
  const float* keys = (const float*)d_in[1];
  const float* values = (const float*)d_in[2];
  const float* presence = (const float*)d_in[3];
  const float* wq = (const float*)d_in[5];
  const float* bq = (const float*)d_in[6];
  const float* wk = (const float*)d_in[7];
  const float* bk = (const float*)d_in[8];
  const float* wv = (const float*)d_in[9];
  const float* bv = (const float*)d_in[10];
  const float* wo = (const float*)d_in[11];
  const float* bo = (const float*)d_in[12];
  float* out = (float*)d_out;

  char* ws = (char*)d_ws;
  const size_t MB = 1048576;
  unsigned short* qin = (unsigned short*)(ws + 0 * MB);    // 16 MiB; reused as attn O
  unsigned short* kin = (unsigned short*)(ws + 16 * MB);   // 16 MiB
  unsigned short* vin = (unsigned short*)(ws + 32 * MB);   // 16 MiB
  unsigned short* qb = (unsigned short*)(ws + 48 * MB);    // 16 MiB
  unsigned short* kb = (unsigned short*)(ws + 64 * MB);    // 16 MiB
  unsigned short* vTg = (unsigned short*)(ws + 80 * MB);   // 16 MiB [B][H][64][M]
  unsigned short* wqT = (unsigned short*)(ws + 96 * MB);   // 2 MiB each
  unsigned short* wkT = (unsigned short*)(ws + 98 * MB);
  unsigned short* wvT = (unsigned short*)(ws + 100 * MB);
  unsigned short* woT = (unsigned short*)(ws + 102 * MB);
  float* pmb = (float*)(ws + 104 * MB);                    // 32 KiB

  mask_kernel<<<32, 256, 0, stream>>>(presence, pmb, 8192);
  cvt3_kernel<<<dim3(8192, 3), 256, 0, stream>>>(queries, keys, values, qin, kin, vin);
  wtrans4_kernel<<<dim3(32, 32, 4), dim3(32, 8), 0, stream>>>(wq, wk, wv, wo, wqT, wkT, wvT,
                                                              woT);
  gemm_qkv_kernel<<<dim3(512, 1, 3), 256, 0, stream>>>(qin, kin, vin, wqT, wkT, wvT, bq, bk,
                                                       bv, qb, kb, vTg);
  attn_kernel<<<dim3(16, 16, 4), 256, 0, stream>>>(qb, kb, vTg, pmb, qin);
  gemm_bt_kernel<<<512, 256, 0, stream>>>(qin, woT, bo, out);
}

// Round 11
// 369.005 us; speedup vs baseline: 1.3792x; 1.0156x over previous
//
#include <hip/hip_runtime.h>

// MultiHeadQKVAttention: B=4, N=M=2048, DK=DV=DKP=DVP=1024, H=16, dh=dv=64.
// 6-launch pipeline: mask -> cvt3(f32->bf16) -> wtrans4 -> batched QKV GEMM
// (256x128-tile counted-vmcnt pipeline, V written pre-transposed) -> flash attn
// -> output GEMM (same pipeline).

#define DI __device__ __forceinline__

typedef float f32x4 __attribute__((ext_vector_type(4)));
typedef __bf16 bf16x8 __attribute__((ext_vector_type(8)));
typedef __bf16 bf16x2 __attribute__((ext_vector_type(2)));
typedef unsigned short ushort8v __attribute__((ext_vector_type(8)));
typedef unsigned int uint4v __attribute__((ext_vector_type(4)));

typedef const __attribute__((address_space(1))) void gvoid_t;
typedef __attribute__((address_space(3))) void lvoid_t;

DI unsigned short f2b(float f) { return __builtin_bit_cast(unsigned short, (__bf16)f); }

DI unsigned pack2(float a, float b) {
  bf16x2 v;
  v[0] = (__bf16)a;
  v[1] = (__bf16)b;
  return __builtin_bit_cast(unsigned, v);
}

DI void swap32(unsigned& x, unsigned& y) {
  asm volatile("v_permlane32_swap_b32 %0, %1" : "+v"(x), "+v"(y));
}
DI void swap16(unsigned& x, unsigned& y) {
  asm volatile("v_permlane16_swap_b32 %0, %1" : "+v"(x), "+v"(y));
}

DI void gload16(const void* g, void* l) {
  __builtin_amdgcn_global_load_lds((gvoid_t*)g, (lvoid_t*)l, 16, 0, 0);
}

// ---------------- batched f32 -> bf16 convert ----------------
__global__ __launch_bounds__(256) void cvt3_kernel(const float* __restrict__ q,
                                                   const float* __restrict__ k,
                                                   const float* __restrict__ v,
                                                   unsigned short* __restrict__ qo,
                                                   unsigned short* __restrict__ ko,
                                                   unsigned short* __restrict__ vo) {
  const int z = blockIdx.y;
  const float* in = z == 0 ? q : z == 1 ? k : v;
  unsigned short* out = z == 0 ? qo : z == 1 ? ko : vo;
  int i = blockIdx.x * 256 + threadIdx.x;
  float4 vv = ((const float4*)in)[i];
  ushort4 o;
  o.x = f2b(vv.x); o.y = f2b(vv.y); o.z = f2b(vv.z); o.w = f2b(vv.w);
  ((ushort4*)out)[i] = o;
}

// ---------------- mask precompute ----------------
__global__ __launch_bounds__(256) void mask_kernel(const float* __restrict__ pres,
                                                   float* __restrict__ pm, int n) {
  int i = blockIdx.x * 256 + threadIdx.x;
  if (i < n) pm[i] = (pres[i] - 1.0f) * 1.8033688011112042e31f;
}

// ---------------- batched weight transpose ----------------
__global__ __launch_bounds__(256) void wtrans4_kernel(const float* __restrict__ w0,
                                                      const float* __restrict__ w1,
                                                      const float* __restrict__ w2,
                                                      const float* __restrict__ w3,
                                                      unsigned short* __restrict__ o0,
                                                      unsigned short* __restrict__ o1,
                                                      unsigned short* __restrict__ o2,
                                                      unsigned short* __restrict__ o3) {
  __shared__ float t[32][33];
  const int z = blockIdx.z;
  const float* in = z == 0 ? w0 : z == 1 ? w1 : z == 2 ? w2 : w3;
  unsigned short* out = z == 0 ? o0 : z == 1 ? o1 : z == 2 ? o2 : o3;
  const int n0 = blockIdx.x * 32, k0 = blockIdx.y * 32;
  const int tx = threadIdx.x, ty = threadIdx.y;
#pragma unroll
  for (int i = 0; i < 4; ++i)
    t[ty + i * 8][tx] = in[(size_t)(k0 + ty + i * 8) * 1024 + n0 + tx];
  __syncthreads();
#pragma unroll
  for (int i = 0; i < 4; ++i)
    out[(size_t)(n0 + ty + i * 8) * 1024 + k0 + tx] = f2b(t[tx][ty + i * 8]);
}

// ---------------- GEMM core: 256x128 tile, BK=64, 8 waves (4M x 2N) ----------------
// 3 LDS buffers (A 32KB + B 16KB each = 48KB; 144KB total), 2-tiles-ahead staging,
// counted vmcnt(6) once per K-tile, raw s_barrier (no vmcnt drain), setprio on MFMA.
// Issue stream per wave: prologue [T0:6, T1:6]; tile t issues T(t+2):6.
// At tile t wait vmcnt(6): newest 6 = T(t+1)'s -> T(t) and older all landed.
DI void stage_a_chunk(const unsigned short* A, size_t rowA, int k0, char* dst, int w,
                      int lane, int i) {
  const int c = w * 4 + i;  // 0..31 chunks of 1KB (A tile 32KB, 256 rows x 128B)
  const int off = c * 1024 + lane * 16;
  const int row = off >> 7;
  const int cb = (off & 127) ^ ((row & 7) << 4);
  gload16(A + (rowA + row) * 1024 + k0 + (cb >> 1), dst + c * 1024);
}
DI void stage_b_chunk(const unsigned short* Bt, int colB, int k0, char* dst, int w,
                      int lane, int i) {
  const int c = w * 2 + i;  // 0..15 chunks (B tile 16KB, 128 rows x 128B)
  const int off = c * 1024 + lane * 16;
  const int row = off >> 7;
  const int cb = (off & 127) ^ ((row & 7) << 4);
  gload16(Bt + (size_t)(colB + row) * 1024 + k0 + (cb >> 1), dst + c * 1024);
}

DI void gemm_core(const unsigned short* __restrict__ A, const unsigned short* __restrict__ Bt,
                  size_t rowA, int colB, char* lds, f32x4 acc[4][4]) {
  const int tid = (int)threadIdx.x;
  const int w = tid >> 6, lane = tid & 63;
  const int lq = lane >> 4, lr = lane & 15;
  const int wm = w >> 1, wn = w & 1;

  char* const buf0 = lds;
  char* const buf1 = lds + 49152;
  char* const buf2 = lds + 98304;

#pragma unroll
  for (int m = 0; m < 4; ++m)
#pragma unroll
    for (int n = 0; n < 4; ++n) acc[m][n] = f32x4{0.f, 0.f, 0.f, 0.f};

  // prologue: stage tiles 0 and 1
#pragma unroll
  for (int i = 0; i < 4; ++i) stage_a_chunk(A, rowA, 0, buf0, w, lane, i);
#pragma unroll
  for (int i = 0; i < 2; ++i) stage_b_chunk(Bt, colB, 0, buf0 + 32768, w, lane, i);
#pragma unroll
  for (int i = 0; i < 4; ++i) stage_a_chunk(A, rowA, 64, buf1, w, lane, i);
#pragma unroll
  for (int i = 0; i < 2; ++i) stage_b_chunk(Bt, colB, 64, buf1 + 32768, w, lane, i);

  for (int t = 0; t < 16; ++t) {
    if (t < 15)
      asm volatile("s_waitcnt vmcnt(6)" ::: "memory");
    else
      asm volatile("s_waitcnt vmcnt(0)" ::: "memory");
    __builtin_amdgcn_s_barrier();
    __builtin_amdgcn_sched_barrier(0);

    const int ti = t % 3;
    char* cur = ti == 0 ? buf0 : ti == 1 ? buf1 : buf2;
    const int ni = (t + 2) % 3;
    char* nxt = ni == 0 ? buf0 : ni == 1 ? buf1 : buf2;
    const bool st = (t + 2) < 16;
    const int kn = (t + 2) * 64;

    bf16x8 bfr[4][2];
#pragma unroll
    for (int n = 0; n < 4; ++n) {
      const int row = wn * 64 + n * 16 + lr;
      const char* base = cur + 32768 + row * 128;
      const int sw = (row & 7) << 4;
      bfr[n][0] = *(const bf16x8*)(base + ((lq * 16) ^ sw));
      bfr[n][1] = *(const bf16x8*)(base + ((64 + lq * 16) ^ sw));
    }
#pragma unroll
    for (int m = 0; m < 4; ++m) {
      const int row = wm * 64 + m * 16 + lr;
      const char* base = cur + row * 128;
      const int sw = (row & 7) << 4;
      const bf16x8 af0 = *(const bf16x8*)(base + ((lq * 16) ^ sw));
      const bf16x8 af1 = *(const bf16x8*)(base + ((64 + lq * 16) ^ sw));
      if (st) {  // interleave stage issues: m0/m1 -> A chunks, m2/m3 -> B chunks
        if (m < 2) {
          stage_a_chunk(A, rowA, kn, nxt, w, lane, m * 2);
          stage_a_chunk(A, rowA, kn, nxt, w, lane, m * 2 + 1);
        } else {
          stage_b_chunk(Bt, colB, kn, nxt + 32768, w, lane, m - 2);
        }
      }
      __builtin_amdgcn_s_setprio(1);
#pragma unroll
      for (int n = 0; n < 4; ++n) {
        acc[m][n] = __builtin_amdgcn_mfma_f32_16x16x32_bf16(af0, bfr[n][0], acc[m][n], 0, 0, 0);
        acc[m][n] = __builtin_amdgcn_mfma_f32_16x16x32_bf16(af1, bfr[n][1], acc[m][n], 0, 0, 0);
      }
      __builtin_amdgcn_s_setprio(0);
    }
  }
}

// Batched QKV projection GEMM. z=0: qb, z=1: kb, z=2: V -> vTg pre-transposed.
__global__ __launch_bounds__(512, 2) void gemm_qkv_kernel(
    const unsigned short* __restrict__ qin, const unsigned short* __restrict__ kin,
    const unsigned short* __restrict__ vin, const unsigned short* __restrict__ wqT,
    const unsigned short* __restrict__ wkT, const unsigned short* __restrict__ wvT,
    const float* __restrict__ bq, const float* __restrict__ bk,
    const float* __restrict__ bv, unsigned short* __restrict__ qb,
    unsigned short* __restrict__ kb, unsigned short* __restrict__ vTg) {
  __shared__ char lds[147456];

  const int z = blockIdx.z;
  const unsigned short* A = z == 0 ? qin : z == 1 ? kin : vin;
  const unsigned short* Bt = z == 0 ? wqT : z == 1 ? wkT : wvT;
  const float* bias = z == 0 ? bq : z == 1 ? bk : bv;

  const int wg0 = (int)blockIdx.x;                  // 256 blocks
  const int wg = (wg0 & 7) * 32 + (wg0 >> 3);       // XCD-bijective swizzle
  const int by = wg >> 3, bx = wg & 7;              // 32 x 8
  const size_t rowA = (size_t)by * 256;
  const int colB = bx * 128;

  const int tid = (int)threadIdx.x;
  const int w = tid >> 6, lane = tid & 63;
  const int lq = lane >> 4, lr = lane & 15;
  const int wm = w >> 1, wn = w & 1;

  f32x4 acc[4][4];
  gemm_core(A, Bt, rowA, colB, lds, acc);

  if (z < 2) {
    unsigned short* C = z == 0 ? qb : kb;
#pragma unroll
    for (int n = 0; n < 4; ++n) {
      const int col = colB + wn * 64 + n * 16 + lr;
      const float bvl = bias[col];
#pragma unroll
      for (int m = 0; m < 4; ++m) {
        const size_t r0 = rowA + wm * 64 + m * 16 + lq * 4;
#pragma unroll
        for (int r = 0; r < 4; ++r) C[(r0 + r) * 1024 + col] = f2b(acc[m][n][r] + bvl);
      }
    }
  } else {
    // V: write transposed vTg[(b*16+h)*64+d][ml], 4 consecutive ml per store
#pragma unroll
    for (int n = 0; n < 4; ++n) {
      const int col = colB + wn * 64 + n * 16 + lr;  // h*64+d
      const float bvl = bias[col];
#pragma unroll
      for (int m = 0; m < 4; ++m) {
        const size_t row0 = rowA + wm * 64 + m * 16 + lq * 4;
        const int bb = (int)(row0 >> 11);
        const int ml = (int)(row0 & 2047);
        ushort4 o;
        o.x = f2b(acc[m][n][0] + bvl);
        o.y = f2b(acc[m][n][1] + bvl);
        o.z = f2b(acc[m][n][2] + bvl);
        o.w = f2b(acc[m][n][3] + bvl);
        *(ushort4*)(vTg + (((size_t)(bb * 1024 + col)) << 11) + ml) = o;
      }
    }
  }
}

// ---------------- output GEMM: C f32 = A @ Bt^T + bias ----------------
__global__ __launch_bounds__(512, 2) void gemm_bt_kernel(const unsigned short* __restrict__ A,
                                                         const unsigned short* __restrict__ Bt,
                                                         const float* __restrict__ bias,
                                                         float* __restrict__ C) {
  __shared__ char lds[147456];

  const int wg0 = (int)blockIdx.x;
  const int wg = (wg0 & 7) * 32 + (wg0 >> 3);
  const int by = wg >> 3, bx = wg & 7;
  const size_t rowA = (size_t)by * 256;
  const int colB = bx * 128;

  const int tid = (int)threadIdx.x;
  const int w = tid >> 6, lane = tid & 63;
  const int lq = lane >> 4, lr = lane & 15;
  const int wm = w >> 1, wn = w & 1;

  f32x4 acc[4][4];
  gemm_core(A, Bt, rowA, colB, lds, acc);

#pragma unroll
  for (int n = 0; n < 4; ++n) {
    const int col = colB + wn * 64 + n * 16 + lr;
    const float bvl = bias[col];
#pragma unroll
    for (int m = 0; m < 4; ++m) {
      const size_t r0 = rowA + wm * 64 + m * 16 + lq * 4;
#pragma unroll
      for (int r = 0; r < 4; ++r) C[(r0 + r) * 1024 + col] = acc[m][n][r] + bvl;
    }
  }
}

// ---------------- Flash attention (unchanged from round 10) ----------------
DI void softmax_pk(f32x4 s[4], float& mrun, float& lrun, f32x4 acc[4], unsigned* pk) {
  float rm = fmaxf(fmaxf(s[0][0], s[0][1]), fmaxf(s[0][2], s[0][3]));
#pragma unroll
  for (int kf = 1; kf < 4; ++kf)
    rm = fmaxf(rm, fmaxf(fmaxf(s[kf][0], s[kf][1]), fmaxf(s[kf][2], s[kf][3])));
  rm = fmaxf(rm, __shfl_xor(rm, 16, 64));
  rm = fmaxf(rm, __shfl_xor(rm, 32, 64));
  if (__any(rm > mrun + 8.0f)) {  // defer-max (T13)
    const float mn = fmaxf(mrun, rm);
    const float al = __builtin_amdgcn_exp2f(mrun - mn);
    lrun *= al;
#pragma unroll
    for (int df = 0; df < 4; ++df) acc[df] *= al;
    mrun = mn;
  }
  float rs = 0.f;
#pragma unroll
  for (int kf = 0; kf < 4; ++kf) {
#pragma unroll
    for (int r = 0; r < 4; ++r) {
      const float p = __builtin_amdgcn_exp2f(s[kf][r] - mrun);
      s[kf][r] = p;
      rs += p;
    }
    pk[kf * 2] = pack2(s[kf][0], s[kf][1]);
    pk[kf * 2 + 1] = pack2(s[kf][2], s[kf][3]);
  }
  rs += __shfl_xor(rs, 16, 64);
  rs += __shfl_xor(rs, 32, 64);
  lrun += rs;
}

DI bf16x8 pv_frag(const unsigned* pk, int kc) {
  unsigned x0 = pk[4 * kc + 0], y0 = pk[4 * kc + 2];
  swap32(x0, y0);
  swap16(x0, y0);
  unsigned x1 = pk[4 * kc + 1], y1 = pk[4 * kc + 3];
  swap32(x1, y1);
  swap16(x1, y1);
  uint4v wds;
  wds[0] = x0; wds[1] = x1; wds[2] = y0; wds[3] = y1;
  return __builtin_bit_cast(bf16x8, wds);
}

__global__ __launch_bounds__(256, 4) void attn_kernel(const unsigned short* __restrict__ Q,
                                                      const unsigned short* __restrict__ K,
                                                      const unsigned short* __restrict__ Vt,
                                                      const float* __restrict__ pm,
                                                      unsigned short* __restrict__ O) {
  __shared__ unsigned short kT[64 * 64];
  __shared__ unsigned short vT[64 * 64];

  const int q0 = blockIdx.x * 128;
  const int h = blockIdx.y, b = blockIdx.z;
  const int tid = (int)threadIdx.x;
  const int w = tid >> 6, lane = tid & 63;
  const int lq = lane >> 4, lr = lane & 15;

  const unsigned short* qp = Q + ((size_t)(b * 2048 + q0 + w * 32 + lr) * 1024 + h * 64);
  const bf16x8 qfA0 = *(const bf16x8*)(qp + lq * 8);
  const bf16x8 qfA1 = *(const bf16x8*)(qp + 32 + lq * 8);
  const bf16x8 qfB0 = *(const bf16x8*)(qp + 16384 + lq * 8);
  const bf16x8 qfB1 = *(const bf16x8*)(qp + 16384 + 32 + lq * 8);

  const int s7 = (lr & 7) << 4;
  const int rd0 = lr * 128 + ((lq * 16) ^ s7);
  const int rd1 = lr * 128 + ((64 + lq * 16) ^ s7);

  const int rowS0 = w * 16 + (lane >> 3), rowS1 = rowS0 + 8;
  const int colS0 = ((lane & 7) * 16) ^ ((rowS0 & 7) << 4);
  const int colS1 = ((lane & 7) * 16) ^ ((rowS1 & 7) << 4);
  const unsigned short* Kb = K + (size_t)(b * 2048) * 1024 + h * 64;
  const unsigned short* Vb = Vt + (size_t)((b * 16 + h) * 64) * 2048;
  const float* pmB = pm + b * 2048;

  f32x4 accA[4], accB[4];
#pragma unroll
  for (int df = 0; df < 4; ++df) {
    accA[df] = f32x4{0.f, 0.f, 0.f, 0.f};
    accB[df] = f32x4{0.f, 0.f, 0.f, 0.f};
  }
  float mA = -3.0e38f, lA = 0.f, mB = -3.0e38f, lB = 0.f;

  for (int m0 = 0; m0 < 2048; m0 += 64) {
    gload16(Kb + (size_t)(m0 + rowS0) * 1024 + (colS0 >> 1), &kT[(w * 2) * 512]);
    gload16(Vb + (size_t)rowS0 * 2048 + m0 + (colS0 >> 1), &vT[(w * 2) * 512]);
    gload16(Kb + (size_t)(m0 + rowS1) * 1024 + (colS1 >> 1), &kT[(w * 2 + 1) * 512]);
    gload16(Vb + (size_t)rowS1 * 2048 + m0 + (colS1 >> 1), &vT[(w * 2 + 1) * 512]);
    __syncthreads();

    f32x4 sA[4], sB[4];
#pragma unroll
    for (int kf = 0; kf < 4; ++kf) {
      sA[kf] = f32x4{0.f, 0.f, 0.f, 0.f};
      sB[kf] = f32x4{0.f, 0.f, 0.f, 0.f};
    }
#pragma unroll
    for (int kk = 0; kk < 2; ++kk) {
      const int rdk = kk ? rd1 : rd0;
      const bf16x8 qa = kk ? qfA1 : qfA0;
      const bf16x8 qb_ = kk ? qfB1 : qfB0;
#pragma unroll
      for (int kf = 0; kf < 4; ++kf) {
        const bf16x8 kfr = *(const bf16x8*)((const char*)kT + rdk + kf * 2048);
        sA[kf] = __builtin_amdgcn_mfma_f32_16x16x32_bf16(kfr, qa, sA[kf], 0, 0, 0);
        sB[kf] = __builtin_amdgcn_mfma_f32_16x16x32_bf16(kfr, qb_, sB[kf], 0, 0, 0);
      }
    }

    const float SC = 0.18033688011112042f;  // 0.125 * log2(e)
#pragma unroll
    for (int kf = 0; kf < 4; ++kf) {
      const f32x4 pv = *(const f32x4*)(pmB + m0 + kf * 16 + lq * 4);
#pragma unroll
      for (int r = 0; r < 4; ++r) {
        sA[kf][r] = sA[kf][r] * SC + pv[r];
        sB[kf][r] = sB[kf][r] * SC + pv[r];
      }
    }

    unsigned pkA[8], pkB[8];
    softmax_pk(sA, mA, lA, accA, pkA);
    softmax_pk(sB, mB, lB, accB, pkB);

#pragma unroll
    for (int kc = 0; kc < 2; ++kc) {
      const int rdk = kc ? rd1 : rd0;
      const bf16x8 pa = pv_frag(pkA, kc);
      const bf16x8 pb = pv_frag(pkB, kc);
#pragma unroll
      for (int df = 0; df < 4; ++df) {
        const bf16x8 vf = *(const bf16x8*)((const char*)vT + rdk + df * 2048);
        accA[df] = __builtin_amdgcn_mfma_f32_16x16x32_bf16(vf, pa, accA[df], 0, 0, 0);
        accB[df] = __builtin_amdgcn_mfma_f32_16x16x32_bf16(vf, pb, accB[df], 0, 0, 0);
      }
    }
    __syncthreads();
  }

  const float rlA = __builtin_amdgcn_rcpf(lA);
  const float rlB = __builtin_amdgcn_rcpf(lB);
  unsigned short* Op = O + ((size_t)(b * 2048 + q0 + w * 32 + lr) * 1024 + h * 64);
#pragma unroll
  for (int df = 0; df < 4; ++df) {
    ushort4 oa, ob;
    oa.x = f2b(accA[df][0] * rlA); oa.y = f2b(accA[df][1] * rlA);
    oa.z = f2b(accA[df][2] * rlA); oa.w = f2b(accA[df][3] * rlA);
    ob.x = f2b(accB[df][0] * rlB); ob.y = f2b(accB[df][1] * rlB);
    ob.z = f2b(accB[df][2] * rlB); ob.w = f2b(accB[df][3] * rlB);
    *(ushort4*)(Op + df * 16 + lq * 4) = oa;
    *(ushort4*)(Op + 16384 + df * 16 + lq * 4) = ob;
  }
}

// ---------------- launch ----------------
extern "C" void kernel_launch(void* const* d_in, const int* in_sizes, int n_in,
                              void* d_out, int out_size, void* d_ws, size_t ws_size,
                              hipStream_t stream) {
  const float* queries = (const float*)d_in[0];
  const float* keys = (const float*)d_in[1];
  const float* values = (const float*)d_in[2];
  const float* presence = (const float*)d_in[3];
  const float* wq = (const float*)d_in[5];
  const float* bq = (const float*)d_in[6];
  const float* wk = (const float*)d_in[7];
  const float* bk = (const float*)d_in[8];
  const float* wv = (const float*)d_in[9];
  const float* bv = (const float*)d_in[10];
  const float* wo = (const float*)d_in[11];
  const float* bo = (const float*)d_in[12];
  float* out = (float*)d_out;

  char* ws = (char*)d_ws;
  const size_t MB = 1048576;
  unsigned short* qin = (unsigned short*)(ws + 0 * MB);    // 16 MiB; reused as attn O
  unsigned short* kin = (unsigned short*)(ws + 16 * MB);   // 16 MiB
  unsigned short* vin = (unsigned short*)(ws + 32 * MB);   // 16 MiB
  unsigned short* qb = (unsigned short*)(ws + 48 * MB);    // 16 MiB
  unsigned short* kb = (unsigned short*)(ws + 64 * MB);    // 16 MiB
  unsigned short* vTg = (unsigned short*)(ws + 80 * MB);   // 16 MiB [B][H][64][M]
  unsigned short* wqT = (unsigned short*)(ws + 96 * MB);   // 2 MiB each
  unsigned short* wkT = (unsigned short*)(ws + 98 * MB);
  unsigned short* wvT = (unsigned short*)(ws + 100 * MB);
  unsigned short* woT = (unsigned short*)(ws + 102 * MB);
  float* pmb = (float*)(ws + 104 * MB);                    // 32 KiB

  mask_kernel<<<32, 256, 0, stream>>>(presence, pmb, 8192);
  cvt3_kernel<<<dim3(8192, 3), 256, 0, stream>>>(queries, keys, values, qin, kin, vin);
  wtrans4_kernel<<<dim3(32, 32, 4), dim3(32, 8), 0, stream>>>(wq, wk, wv, wo, wqT, wkT, wvT,
                                                              woT);
  gemm_qkv_kernel<<<dim3(256, 1, 3), 512, 0, stream>>>(qin, kin, vin, wqT, wkT, wvT, bq, bk,
                                                       bv, qb, kb, vTg);
  attn_kernel<<<dim3(16, 16, 4), 256, 0, stream>>>(qb, kb, vTg, pmb, qin);
  gemm_bt_kernel<<<256, 512, 0, stream>>>(qin, woT, bo, out);
}